// Round 10
// baseline (392.605 us; speedup 1.0000x reference)
//
#include <hip/hip_runtime.h>
#include <hip/hip_bf16.h>
#include <math.h>
#include <float.h>

#define N_S   32768
#define K_C   2048
#define D_DIM 512
#define KD    (K_C * D_DIM)
#define MARGIN 1.0f      // hi*hi-only approx: ~8-sigma of distance-error (sd~0.09) + gap slack
#define FB_MARGIN 0.02f  // fallback path (3-term split) margin

using s16x8 = __attribute__((ext_vector_type(8))) short;
using f32x4 = __attribute__((ext_vector_type(4))) float;

typedef const __attribute__((address_space(1))) unsigned int glb_u32_t;
typedef __attribute__((address_space(3))) unsigned int lds_u32_t;

__device__ __forceinline__ void gll16(const void* g, void* l) {
  __builtin_amdgcn_global_load_lds((glb_u32_t*)g, (lds_u32_t*)l, 16, 0, 0);
}

__device__ inline void cvt_hl(float x, ushort& hb, ushort& lb) {
  __hip_bfloat16 h = __float2bfloat16(x);
  hb = *reinterpret_cast<ushort*>(&h);
  float hf = __bfloat162float(h);
  __hip_bfloat16 l = __float2bfloat16(x - hf);
  lb = *reinterpret_cast<ushort*>(&l);
}

__device__ inline void top2_merge(float& a1, int& ai, float& a2, float b1, int bi, float b2) {
  if (b1 < a1 || (b1 == a1 && bi < ai)) { a2 = fminf(a1, b2); a1 = b1; ai = bi; }
  else { a2 = fminf(a2, b1); }
}

// ================================================================ FAST PATH

// Convert fp32 -> hi bf16 only, pre-tiled+swizzled; fused row norms.
__global__ void preconvert_kernel(const float* __restrict__ S, const float* __restrict__ M,
                                  ushort* __restrict__ Aq, ushort* __restrict__ Bq,
                                  float* __restrict__ snorm, float* __restrict__ mnorm) {
  int row = blockIdx.x * 4 + (threadIdx.x >> 6);
  int l   = threadIdx.x & 63;
  bool isS = row < N_S;
  int lr = isS ? row : row - N_S;
  const float* src = (isS ? S : M) + (size_t)lr * D_DIM + l * 8;
  float4 u0 = *(const float4*)(src);
  float4 u1 = *(const float4*)(src + 4);
  float x[8] = {u0.x, u0.y, u0.z, u0.w, u1.x, u1.y, u1.z, u1.w};
  s16x8 hv;
  float nrm = 0.f;
#pragma unroll
  for (int i = 0; i < 8; ++i) {
    nrm += x[i] * x[i];
    __hip_bfloat16 h = __float2bfloat16(x[i]);
    hv[i] = *reinterpret_cast<short*>(&h);
  }
  int r = lr & 127, tile = lr >> 7;
  int kc = l >> 3, slot = (l & 7) ^ (r & 7);
  ushort* dst = isS ? Aq : Bq;
  size_t base = ((size_t)(tile * 8 + kc) * 128 + r) * 64 + slot * 8;
  *(s16x8*)(dst + base) = hv;
  for (int off = 32; off; off >>= 1) nrm += __shfl_down(nrm, off);
  if (l == 0) { if (isS) snorm[lr] = nrm; else mnorm[lr] = nrm; }
}

// 128x256 tile hi*hi bf16 GEMM (-2*S.M approx) + fused per-row top-2 partials.
// 4 waves, per-wave 64 rows x 128 cols (acc[4][8]); 2-barrier proven loop.
__launch_bounds__(256)
__global__ void gemm_top2_kernel(const ushort* __restrict__ Aq, const ushort* __restrict__ Bq,
                                 const float* __restrict__ mnorm,
                                 float* __restrict__ pval, int* __restrict__ pidx,
                                 float* __restrict__ pm2) {
  __shared__ __align__(16) ushort lA[128 * 64];   // 16 KiB
  __shared__ __align__(16) ushort lB[256 * 64];   // 32 KiB (two 128-row sub-tiles)
  __shared__ float rv1[128 * 2], rv2[128 * 2];
  __shared__ int   ri1[128 * 2];
  const int t = threadIdx.x, lane = t & 63, wid = t >> 6;
  const int wr = wid >> 1, wc = wid & 1;          // per-wave: rows wr*64, cols wc*128
  const int lx = lane & 15, kg = lane >> 4;
  // 2048 blocks; 8 consecutive per XCD share rt (A-panel L2 reuse)
  int bid = ((int)blockIdx.x & 7) * 256 + ((int)blockIdx.x >> 3);
  const int rt = bid >> 3, ct = bid & 7;

  f32x4 acc[4][8];
#pragma unroll
  for (int i = 0; i < 4; ++i)
#pragma unroll
    for (int j = 0; j < 8; ++j) { acc[i][j][0] = 0.f; acc[i][j][1] = 0.f; acc[i][j][2] = 0.f; acc[i][j][3] = 0.f; }

  for (int s = 0; s < 8; ++s) {
    const char* ga  = (const char*)(Aq + ((size_t)(rt * 8 + s) << 13));
    const char* gb0 = (const char*)(Bq + ((size_t)((2 * ct + 0) * 8 + s) << 13));
    const char* gb1 = (const char*)(Bq + ((size_t)((2 * ct + 1) * 8 + s) << 13));
    __syncthreads();
#pragma unroll
    for (int q = 0; q < 4; ++q) {
      gll16(ga  + wid * 1024 + lane * 16 + q * 4096, (char*)lA + wid * 1024 + q * 4096);
      gll16(gb0 + wid * 1024 + lane * 16 + q * 4096, (char*)lB + wid * 1024 + q * 4096);
      gll16(gb1 + wid * 1024 + lane * 16 + q * 4096, (char*)lB + 16384 + wid * 1024 + q * 4096);
    }
    __syncthreads();
#pragma unroll
    for (int kk = 0; kk < 2; ++kk) {
      s16x8 af[4], bf[8];
#pragma unroll
      for (int i = 0; i < 4; ++i) {
        int r = wr * 64 + i * 16 + lx;
        af[i] = *(const s16x8*)&lA[r * 64 + (((kk * 4 + kg) ^ (lx & 7)) * 8)];
      }
#pragma unroll
      for (int j = 0; j < 8; ++j) {
        int r = wc * 128 + j * 16 + lx;
        bf[j] = *(const s16x8*)&lB[r * 64 + (((kk * 4 + kg) ^ (lx & 7)) * 8)];
      }
#pragma unroll
      for (int i = 0; i < 4; ++i)
#pragma unroll
        for (int j = 0; j < 8; ++j)
          acc[i][j] = __builtin_amdgcn_mfma_f32_16x16x32_bf16(af[i], bf[j], acc[i][j], 0, 0, 0);
    }
  }

  float mn[8];
#pragma unroll
  for (int j = 0; j < 8; ++j) mn[j] = mnorm[ct * 256 + wc * 128 + j * 16 + lx];
#pragma unroll
  for (int i = 0; i < 4; ++i)
#pragma unroll
    for (int reg = 0; reg < 4; ++reg) {
      float v1 = FLT_MAX, v2 = FLT_MAX; int i1 = 0;
#pragma unroll
      for (int j = 0; j < 8; ++j) {               // j ascending => k ascending
        float v = mn[j] - 2.f * acc[i][j][reg];
        int k = ct * 256 + wc * 128 + j * 16 + lx;
        if (v < v1) { v2 = v1; v1 = v; i1 = k; } else v2 = fminf(v2, v);
      }
#pragma unroll
      for (int msk = 1; msk < 16; msk <<= 1) {
        float o1 = __shfl_xor(v1, msk);
        int   oi = __shfl_xor(i1, msk);
        float o2 = __shfl_xor(v2, msk);
        top2_merge(v1, i1, v2, o1, oi, o2);
      }
      if (lx == 0) {
        int rowr = wr * 64 + i * 16 + kg * 4 + reg;
        rv1[rowr * 2 + wc] = v1; ri1[rowr * 2 + wc] = i1; rv2[rowr * 2 + wc] = v2;
      }
    }
  __syncthreads();
  if (t < 128) {
    float a1 = rv1[t * 2], a2 = rv2[t * 2]; int ai = ri1[t * 2];   // wc=0: lower k's first
    top2_merge(a1, ai, a2, rv1[t * 2 + 1], ri1[t * 2 + 1], rv2[t * 2 + 1]);
    size_t n = (size_t)rt * 128 + t;
    pval[n * 8 + ct] = a1;
    pidx[n * 8 + ct] = ai;
    pm2 [n * 8 + ct] = a2;
  }
}

// merge 8 col-tile partials; flag ambiguous; emit DENSE (sample,tile) rescue worklist
// via wave-aggregated atomics; count + inertia for sure rows.
__global__ void merge2_kernel(const float* __restrict__ pval, const int* __restrict__ pidx,
                              const float* __restrict__ pm2, const float* __restrict__ snorm,
                              int* __restrict__ bins, float* __restrict__ inertia,
                              int* __restrict__ counts,
                              int* __restrict__ flag_list, int* __restrict__ flag_count,
                              int* __restrict__ worklist, int* __restrict__ wl_count,
                              unsigned long long* __restrict__ keys) {
  int n = blockIdx.x * 256 + threadIdx.x;
  int lane = threadIdx.x & 63;
  float pv[8], p2[8]; int pi[8];
#pragma unroll
  for (int c = 0; c < 8; ++c) {
    pv[c] = pval[(size_t)n * 8 + c];
    pi[c] = pidx[(size_t)n * 8 + c];
    p2[c] = pm2 [(size_t)n * 8 + c];
  }
  float a1 = FLT_MAX, a2 = FLT_MAX; int ai = 0x7fffffff;
#pragma unroll
  for (int c = 0; c < 8; ++c)
    top2_merge(a1, ai, a2, pv[c], pi[c], p2[c]);
  bool flg = (a2 - a1 <= MARGIN);
  float r = 0.f;
  if (flg) {
    keys[n] = ~0ull;
  } else {
    bins[n] = ai;
    atomicAdd(&counts[ai], 1);
    r = sqrtf(fmaxf(snorm[n] + a1, 0.f));
  }
  // flag_list append (wave-aggregated)
  {
    unsigned long long mask = __ballot(flg);
    if (mask) {
      int leader = __ffsll((unsigned long long)mask) - 1;
      int base = 0;
      if (lane == leader) base = atomicAdd(flag_count, __popcll(mask));
      base = __shfl(base, leader);
      if (flg) flag_list[base + __popcll(mask & ((1ull << lane) - 1))] = n;
    }
  }
  // worklist append: 256-cluster tiles that can contain the exact winner
#pragma unroll
  for (int c = 0; c < 8; ++c) {
    bool want = flg && (pv[c] <= a1 + MARGIN);
    unsigned long long mask = __ballot(want);
    if (mask) {
      int leader = __ffsll((unsigned long long)mask) - 1;
      int base = 0;
      if (lane == leader) base = atomicAdd(wl_count, __popcll(mask));
      base = __shfl(base, leader);
      if (want) worklist[base + __popcll(mask & ((1ull << lane) - 1))] = (n << 3) | c;
    }
  }
  for (int off = 32; off; off >>= 1) r += __shfl_down(r, off);
  if (lane == 0) atomicAdd(inertia, r);
}

// dense-worklist exact fp32 rescue: one item = (sample, 256-cluster tile);
// coalesced M reads (L2-resident), packed-u64 atomicMin argmin.
__launch_bounds__(256)
__global__ void cleanup_work_kernel(const float* __restrict__ S, const float* __restrict__ M,
                                    const float* __restrict__ mnorm,
                                    const int* __restrict__ worklist, const int* __restrict__ wl_count,
                                    unsigned long long* __restrict__ keys) {
  const int t = threadIdx.x, lane = t & 63, w = t >> 6;
  const int items = *wl_count;
  for (int it = blockIdx.x; it < items; it += gridDim.x) {
    int wi = worklist[it];
    int n = wi >> 3, tile = wi & 7;
    const float4* sp = (const float4*)(S + (size_t)n * D_DIM + lane * 8);
    float4 s0 = sp[0], s1 = sp[1];
    int kb = tile * 256 + w * 64;
    unsigned long long bestkey = ~0ull;
    for (int ro = 0; ro < 8; ++ro) {
      float p[8];
#pragma unroll
      for (int rj = 0; rj < 8; ++rj) {
        const float4* mr = (const float4*)(M + (size_t)(kb + ro * 8 + rj) * D_DIM + lane * 8);
        float4 a = mr[0], b = mr[1];
        p[rj] = a.x*s0.x + a.y*s0.y + a.z*s0.z + a.w*s0.w
              + b.x*s1.x + b.y*s1.y + b.z*s1.z + b.w*s1.w;
      }
#pragma unroll
      for (int rj = 0; rj < 8; ++rj)
#pragma unroll
        for (int off = 1; off < 64; off <<= 1) p[rj] += __shfl_xor(p[rj], off);
#pragma unroll
      for (int rj = 0; rj < 8; ++rj) {
        int k = kb + ro * 8 + rj;
        float dist = mnorm[k] - 2.f * p[rj];
        unsigned u = __float_as_uint(dist);
        u = (u >> 31) ? ~u : (u | 0x80000000u);
        unsigned long long key = ((unsigned long long)u << 32) | (unsigned)k;
        bestkey = bestkey < key ? bestkey : key;
      }
    }
    if (lane == 0) atomicMin(keys + n, bestkey);
  }
}

__global__ void cleanup_resolve_kernel(const int* __restrict__ flag_list, const int* __restrict__ flag_count,
                                       const unsigned long long* __restrict__ keys,
                                       const float* __restrict__ snorm,
                                       int* __restrict__ bins, int* __restrict__ counts,
                                       float* __restrict__ inertia) {
  int cnt = *flag_count;
  int i = blockIdx.x * 256 + threadIdx.x;
  float r = 0.f;
  if (i < cnt) {
    int n = flag_list[i];
    unsigned long long key = keys[n];
    int k = (int)(unsigned)(key & 0xffffffffu);
    unsigned u = (unsigned)(key >> 32);
    u = (u >> 31) ? (u & 0x7fffffffu) : ~u;
    float dist = __uint_as_float(u);
    bins[n] = k;
    atomicAdd(&counts[k], 1);
    r = sqrtf(fmaxf(snorm[n] + dist, 0.f));
  }
  for (int off = 32; off; off >>= 1) r += __shfl_down(r, off);
  if ((threadIdx.x & 63) == 0) atomicAdd(inertia, r);
}

// exclusive prefix sum over 2048 counts — single wave, shfl scan (no barriers)
__global__ void prefix_kernel(const int* __restrict__ counts, int* __restrict__ cursor) {
  int l = threadIdx.x;               // 0..63
  int loc[32]; int s = 0;
#pragma unroll
  for (int i = 0; i < 32; ++i) { loc[i] = s; s += counts[l * 32 + i]; }
  int tot = s;
#pragma unroll
  for (int off = 1; off < 64; off <<= 1) {
    int v = __shfl_up(tot, off);
    if (l >= off) tot += v;
  }
  int base = tot - s;
#pragma unroll
  for (int i = 0; i < 32; ++i) cursor[l * 32 + i] = base + loc[i];
}

// bucket-fill: cluster-sorted sample list + per-slot cluster id
__global__ void fill_kernel(const int* __restrict__ bins, int* __restrict__ cursor,
                            int* __restrict__ bucket, int* __restrict__ bcl) {
  int n = blockIdx.x * 256 + threadIdx.x;
  int b = bins[n];
  int pos = atomicAdd(&cursor[b], 1);
  bucket[pos] = n;
  bcl[pos] = b;
}

// segment-scatter: each block owns a fixed 64-entry segment of the sorted bucket;
// register-accumulate runs of equal cluster, flush one atomicAdd per run.
__launch_bounds__(256)
__global__ void segscatter_kernel(const float* __restrict__ S, const int* __restrict__ bucket,
                                  const int* __restrict__ bcl, float* __restrict__ out) {
  __shared__ int sn[64], sk[64];
  const int t = threadIdx.x;
  const int i0 = blockIdx.x * 64;
  if (t < 64) { sn[t] = bucket[i0 + t]; sk[t] = bcl[i0 + t]; }
  __syncthreads();
  float a0 = 0.f, a1 = 0.f;
  int cur = sk[0];
  for (int i = 0; i < 64; ++i) {
    int k = sk[i];
    if (k != cur) {
      atomicAdd(&out[(size_t)cur * D_DIM + t], a0);
      atomicAdd(&out[(size_t)cur * D_DIM + t + 256], a1);
      a0 = 0.f; a1 = 0.f; cur = k;
    }
    const float* row = S + (size_t)sn[i] * D_DIM;
    a0 += row[t];
    a1 += row[t + 256];
  }
  atomicAdd(&out[(size_t)cur * D_DIM + t], a0);
  atomicAdd(&out[(size_t)cur * D_DIM + t + 256], a1);
}

// finalize: out currently holds cluster_sums; apply (sum + m*w)*alpha / keep-old rule
__global__ void finalize2_kernel(const float* __restrict__ M, const float* __restrict__ W,
                                 const int* __restrict__ counts, float* __restrict__ out) {
  int idx = blockIdx.x * 256 + threadIdx.x;
  int k = idx >> 9;
  int cnt = counts[k];
  float w = W[k];
  float nw = w + (float)cnt;
  float alpha = 1.f / ((nw == 0.f) ? 1.f : nw);
  float m = M[idx];
  float v = (out[idx] + m * w) * alpha;
  out[idx] = (cnt == 0) ? m : v;
}

// ============================================================ FALLBACK PATH (round-2)

#define TM    128
#define BK2   32
#define SPLIT 2
#define KPER  (K_C / SPLIT)
#define NKT   (KPER / TM)
#define NDT   (D_DIM / BK2)

__global__ void row_norms_kernel(const float* __restrict__ S, const float* __restrict__ M,
                                 float* __restrict__ snorm, float* __restrict__ mnorm) {
  int row  = blockIdx.x * 4 + (threadIdx.x >> 6);
  int lane = threadIdx.x & 63;
  if (row >= N_S + K_C) return;
  const float* src;
  float* dst;
  if (row < N_S) { src = S + (size_t)row * D_DIM; dst = snorm + row; }
  else { int r = row - N_S; src = M + (size_t)r * D_DIM; dst = mnorm + r; }
  float4 v0 = *(const float4*)(src + lane * 4);
  float4 v1 = *(const float4*)(src + 256 + lane * 4);
  float s = v0.x*v0.x + v0.y*v0.y + v0.z*v0.z + v0.w*v0.w
          + v1.x*v1.x + v1.y*v1.y + v1.z*v1.z + v1.w*v1.w;
  for (int off = 32; off; off >>= 1) s += __shfl_down(s, off);
  if (lane == 0) *dst = s;
}

__launch_bounds__(256)
__global__ void dist_argmin_kernel(const float* __restrict__ S, const float* __restrict__ M,
                                   const float* __restrict__ mnorm,
                                   float* __restrict__ pval, int* __restrict__ pidx,
                                   float* __restrict__ pm2) {
  __shared__ ushort tiles[2][4][TM * BK2];
  __shared__ float sm1[TM * 2];
  __shared__ float sm2[TM * 2];
  __shared__ int   si1[TM * 2];
  const int t    = threadIdx.x;
  const int lane = t & 63, wid = t >> 6;
  const int wr   = wid >> 1, wc = wid & 1;
  const int lx   = lane & 15, kg = lane >> 4;
  const int stile = blockIdx.x >> 1, split = blockIdx.x & 1;
  const int srow0 = stile * TM;
  const int kcol0 = split * KPER;
  for (int i = t; i < TM * 2; i += 256) { sm1[i] = FLT_MAX; sm2[i] = FLT_MAX; si1[i] = 0; }
  float4 av[4], bv[4];
#define LOADREGS(dtoff) do { \
    const float* Ag = S + (size_t)srow0 * D_DIM + (dtoff); \
    const float* Bg = M + (size_t)kbase * D_DIM + (dtoff); \
    _Pragma("unroll") \
    for (int q = 0; q < 4; ++q) { \
      int id = t + q * 256; int r_ = id >> 3, c_ = (id & 7) * 4; \
      av[q] = *(const float4*)(Ag + (size_t)r_ * D_DIM + c_); \
      bv[q] = *(const float4*)(Bg + (size_t)r_ * D_DIM + c_); \
    } } while (0)
#define WRITETILE(buf) do { \
    _Pragma("unroll") \
    for (int q = 0; q < 4; ++q) { \
      int id = t + q * 256; int r_ = id >> 3, c_ = (id & 7) * 4; \
      ushort4 h4, l4; \
      cvt_hl(av[q].x, h4.x, l4.x); cvt_hl(av[q].y, h4.y, l4.y); \
      cvt_hl(av[q].z, h4.z, l4.z); cvt_hl(av[q].w, h4.w, l4.w); \
      *(ushort4*)&tiles[buf][0][r_ * BK2 + c_] = h4; \
      *(ushort4*)&tiles[buf][1][r_ * BK2 + c_] = l4; \
      cvt_hl(bv[q].x, h4.x, l4.x); cvt_hl(bv[q].y, h4.y, l4.y); \
      cvt_hl(bv[q].z, h4.z, l4.z); cvt_hl(bv[q].w, h4.w, l4.w); \
      *(ushort4*)&tiles[buf][2][r_ * BK2 + c_] = h4; \
      *(ushort4*)&tiles[buf][3][r_ * BK2 + c_] = l4; \
    } } while (0)
  for (int kt = 0; kt < NKT; ++kt) {
    const int kbase = kcol0 + kt * TM;
    f32x4 acc[4][4];
#pragma unroll
    for (int i = 0; i < 4; ++i)
#pragma unroll
      for (int j = 0; j < 4; ++j) { acc[i][j][0] = 0.f; acc[i][j][1] = 0.f; acc[i][j][2] = 0.f; acc[i][j][3] = 0.f; }
    float mn[4];
#pragma unroll
    for (int ni = 0; ni < 4; ++ni) mn[ni] = mnorm[kbase + wc * 64 + ni * 16 + lx];
    LOADREGS(0);
    WRITETILE(0);
    __syncthreads();
    for (int di = 0; di < NDT; ++di) {
      const int cur = di & 1;
      if (di + 1 < NDT) LOADREGS((di + 1) * BK2);
      {
        s16x8 ah[4], al[4], bh[4], bl[4];
#pragma unroll
        for (int i = 0; i < 4; ++i) {
          ah[i] = *(const s16x8*)&tiles[cur][0][(wr * 64 + i * 16 + lx) * BK2 + kg * 8];
          al[i] = *(const s16x8*)&tiles[cur][1][(wr * 64 + i * 16 + lx) * BK2 + kg * 8];
          bh[i] = *(const s16x8*)&tiles[cur][2][(wc * 64 + i * 16 + lx) * BK2 + kg * 8];
          bl[i] = *(const s16x8*)&tiles[cur][3][(wc * 64 + i * 16 + lx) * BK2 + kg * 8];
        }
#pragma unroll
        for (int i = 0; i < 4; ++i)
#pragma unroll
          for (int j = 0; j < 4; ++j) {
            acc[i][j] = __builtin_amdgcn_mfma_f32_16x16x32_bf16(ah[i], bh[j], acc[i][j], 0, 0, 0);
            acc[i][j] = __builtin_amdgcn_mfma_f32_16x16x32_bf16(ah[i], bl[j], acc[i][j], 0, 0, 0);
            acc[i][j] = __builtin_amdgcn_mfma_f32_16x16x32_bf16(al[i], bh[j], acc[i][j], 0, 0, 0);
          }
      }
      if (di + 1 < NDT) { WRITETILE(cur ^ 1); __syncthreads(); }
    }
#pragma unroll
    for (int mi = 0; mi < 4; ++mi)
#pragma unroll
      for (int r = 0; r < 4; ++r) {
        float v1 = FLT_MAX, v2 = FLT_MAX; int i1 = 0;
#pragma unroll
        for (int ni = 0; ni < 4; ++ni) {
          float v = mn[ni] - 2.f * acc[mi][ni][r];
          int k = kbase + wc * 64 + ni * 16 + lx;
          if (v < v1) { v2 = v1; v1 = v; i1 = k; } else { v2 = fminf(v2, v); }
        }
#pragma unroll
        for (int msk = 1; msk < 16; msk <<= 1) {
          float o1 = __shfl_xor(v1, msk);
          int   oi = __shfl_xor(i1, msk);
          float o2 = __shfl_xor(v2, msk);
          top2_merge(v1, i1, v2, o1, oi, o2);
        }
        if (lx == 0) {
          int row = wr * 64 + mi * 16 + kg * 4 + r;
          int s = row * 2 + wc;
          float a1 = sm1[s], a2 = sm2[s]; int ai = si1[s];
          top2_merge(a1, ai, a2, v1, i1, v2);
          sm1[s] = a1; sm2[s] = a2; si1[s] = ai;
        }
      }
  }
  __syncthreads();
  if (t < TM) {
    float a1 = sm1[t * 2], a2 = sm2[t * 2]; int ai = si1[t * 2];
    top2_merge(a1, ai, a2, sm1[t * 2 + 1], si1[t * 2 + 1], sm2[t * 2 + 1]);
    int n = srow0 + t;
    pval[n * SPLIT + split] = a1;
    pidx[n * SPLIT + split] = ai;
    pm2[n * SPLIT + split]  = a2;
  }
#undef LOADREGS
#undef WRITETILE
}

__global__ void merge_bins_kernel(const float* __restrict__ pval, const int* __restrict__ pidx,
                                  const float* __restrict__ pm2, const float* __restrict__ snorm,
                                  int* __restrict__ bins, float* __restrict__ inertia,
                                  int* __restrict__ flag_list, int* __restrict__ flag_count) {
  int n = blockIdx.x * 256 + threadIdx.x;
  float a1 = pval[n * SPLIT], a2 = pm2[n * SPLIT]; int ai = pidx[n * SPLIT];
  top2_merge(a1, ai, a2, pval[n * SPLIT + 1], pidx[n * SPLIT + 1], pm2[n * SPLIT + 1]);
  float r = 0.f;
  if (a2 - a1 <= FB_MARGIN) {
    int idx = atomicAdd(flag_count, 1);
    flag_list[idx] = n;
  } else {
    bins[n] = ai;
    r = sqrtf(fmaxf(snorm[n] + a1, 0.f));
  }
  for (int off = 32; off; off >>= 1) r += __shfl_down(r, off);
  if ((threadIdx.x & 63) == 0) atomicAdd(inertia, r);
}

__launch_bounds__(256)
__global__ void cleanup_kernel(const float* __restrict__ S, const float* __restrict__ M,
                               const float* __restrict__ snorm, const float* __restrict__ mnorm,
                               const int* __restrict__ flag_list, const int* __restrict__ flag_count,
                               int* __restrict__ bins, float* __restrict__ inertia) {
  __shared__ float sS[D_DIM];
  __shared__ float wv[4];
  __shared__ int   wk[4];
  const int t = threadIdx.x, lane = t & 63, wid = t >> 6;
  const int cnt = *flag_count;
  for (int fi = blockIdx.x; fi < cnt; fi += gridDim.x) {
    int n = flag_list[fi];
    __syncthreads();
    for (int i = t; i < D_DIM; i += 256) sS[i] = S[(size_t)n * D_DIM + i];
    __syncthreads();
    float best = FLT_MAX; int bk = 0;
    for (int k = wid; k < K_C; k += 4) {
      const float* mr = M + (size_t)k * D_DIM;
      float4 m0 = *(const float4*)(mr + lane * 8);
      float4 m1 = *(const float4*)(mr + lane * 8 + 4);
      float4 s0 = *(const float4*)(sS + lane * 8);
      float4 s1 = *(const float4*)(sS + lane * 8 + 4);
      float p = m0.x*s0.x + m0.y*s0.y + m0.z*s0.z + m0.w*s0.w
              + m1.x*s1.x + m1.y*s1.y + m1.z*s1.z + m1.w*s1.w;
      for (int msk = 1; msk < 64; msk <<= 1) p += __shfl_xor(p, msk);
      float dist = mnorm[k] - 2.f * p;
      if (dist < best) { best = dist; bk = k; }
    }
    if (lane == 0) { wv[wid] = best; wk[wid] = bk; }
    __syncthreads();
    if (t == 0) {
      float b = wv[0]; int bi = wk[0];
      for (int w = 1; w < 4; ++w)
        if (wv[w] < b || (wv[w] == b && wk[w] < bi)) { b = wv[w]; bi = wk[w]; }
      bins[n] = bi;
      atomicAdd(inertia, sqrtf(fmaxf(snorm[n] + b, 0.f)));
    }
  }
}

__global__ void scatter_kernel(const float* __restrict__ S, const int* __restrict__ bins,
                               float* __restrict__ csum, float* __restrict__ counts) {
  int w    = (blockIdx.x * 256 + threadIdx.x) >> 6;
  int lane = threadIdx.x & 63;
  if (w >= N_S) return;
  int b = bins[w];
  const float* src = S + (size_t)w * D_DIM;
  float* dst = csum + (size_t)b * D_DIM;
#pragma unroll
  for (int c = 0; c < D_DIM; c += 64) atomicAdd(dst + c + lane, src[c + lane]);
  if (lane == 0) atomicAdd(counts + b, 1.0f);
}

__global__ void finalize_kernel(const float* __restrict__ M, const float* __restrict__ W,
                                const float* __restrict__ counts, float* __restrict__ out) {
  int idx = blockIdx.x * 256 + threadIdx.x;
  int k = idx >> 9;
  float cnt = counts[k];
  float w   = W[k];
  float nw  = w + cnt;
  float alpha = 1.f / ((nw == 0.f) ? 1.f : nw);
  float m = M[idx];
  float v = (out[idx] + m * w) * alpha;
  out[idx] = (cnt == 0.f) ? m : v;
}

// ================================================================= launcher

extern "C" void kernel_launch(void* const* d_in, const int* in_sizes, int n_in,
                              void* d_out, int out_size, void* d_ws, size_t ws_size,
                              hipStream_t stream) {
  const float* S = (const float*)d_in[0];
  const float* M = (const float*)d_in[1];
  const float* W = (const float*)d_in[2];
  float* out = (float*)d_out;
  char* ws = (char*)d_ws;

  const size_t oA  = 0;                                // A' hi 32 MiB
  const size_t oB  = oA  + (size_t)N_S * 1024;         // B' hi 2 MiB
  const size_t oPV = oB  + (size_t)K_C * 1024;         // pval [N][8]
  const size_t oPM = oPV + (size_t)N_S * 8 * 4;
  const size_t oPI = oPM + (size_t)N_S * 8 * 4;
  const size_t oSN = oPI + (size_t)N_S * 8 * 4;        // snorm
  const size_t oMN = oSN + (size_t)N_S * 4;            // mnorm
  const size_t oBI = oMN + (size_t)K_C * 4;            // bins
  const size_t oCN = oBI + (size_t)N_S * 4;            // counts (int)
  const size_t oCU = oCN + (size_t)K_C * 4;            // cursor
  const size_t oBK = oCU + (size_t)K_C * 4;            // bucket
  const size_t oBC = oBK + (size_t)N_S * 4;            // bcl
  const size_t oFC = oBC + (size_t)N_S * 4;            // flag_count + wl_count (64B)
  const size_t oFL = oFC + 64;                         // flag_list
  const size_t oKY = oFL + (size_t)N_S * 4;            // keys (u64)
  const size_t oWL = oKY + (size_t)N_S * 8;            // worklist (up to 8 per sample)
  const size_t NEED = oWL + (size_t)N_S * 8 * 4;

  if (ws_size >= NEED) {
    ushort* Aq = (ushort*)(ws + oA);
    ushort* Bq = (ushort*)(ws + oB);
    float* pval = (float*)(ws + oPV);
    float* pm2  = (float*)(ws + oPM);
    int*   pidx = (int*)(ws + oPI);
    float* snorm = (float*)(ws + oSN);
    float* mnorm = (float*)(ws + oMN);
    int* bins   = (int*)(ws + oBI);
    int* counts = (int*)(ws + oCN);
    int* cursor = (int*)(ws + oCU);
    int* bucket = (int*)(ws + oBK);
    int* bcl    = (int*)(ws + oBC);
    int* flag_count = (int*)(ws + oFC);
    int* wl_count   = flag_count + 1;
    int* flag_list  = (int*)(ws + oFL);
    unsigned long long* keys = (unsigned long long*)(ws + oKY);
    int* worklist = (int*)(ws + oWL);

    hipMemsetAsync(d_out, 0, (size_t)(KD + 1) * sizeof(float), stream);
    hipMemsetAsync(counts, 0, (size_t)K_C * 4, stream);
    hipMemsetAsync(flag_count, 0, 64, stream);   // zeroes flag_count AND wl_count

    preconvert_kernel<<<(N_S + K_C) / 4, 256, 0, stream>>>(S, M, Aq, Bq, snorm, mnorm);
    gemm_top2_kernel<<<2048, 256, 0, stream>>>(Aq, Bq, mnorm, pval, pidx, pm2);
    merge2_kernel<<<N_S / 256, 256, 0, stream>>>(pval, pidx, pm2, snorm, bins, out + KD,
                                                 counts, flag_list, flag_count,
                                                 worklist, wl_count, keys);
    cleanup_work_kernel<<<4096, 256, 0, stream>>>(S, M, mnorm, worklist, wl_count, keys);
    cleanup_resolve_kernel<<<N_S / 256, 256, 0, stream>>>(flag_list, flag_count, keys, snorm,
                                                          bins, counts, out + KD);
    prefix_kernel<<<1, 64, 0, stream>>>(counts, cursor);
    fill_kernel<<<N_S / 256, 256, 0, stream>>>(bins, cursor, bucket, bcl);
    segscatter_kernel<<<N_S / 64, 256, 0, stream>>>(S, bucket, bcl, out);
    finalize2_kernel<<<KD / 256, 256, 0, stream>>>(M, W, counts, out);
  } else {
    float* mnorm     = (float*)ws;
    float* snorm     = mnorm + K_C;
    int*   bins      = (int*)(snorm + N_S);
    float* counts    = (float*)(bins + N_S);
    float* pval      = counts + K_C;
    int*   pidx      = (int*)(pval + (size_t)N_S * 2);
    float* pm2       = (float*)(pidx + (size_t)N_S * 2);
    int*   flag_count= (int*)(pm2 + (size_t)N_S * 2);
    int*   flag_list = flag_count + 16;

    hipMemsetAsync(d_out, 0, (size_t)(KD + 1) * sizeof(float), stream);
    hipMemsetAsync(counts, 0, K_C * sizeof(float), stream);
    hipMemsetAsync(flag_count, 0, sizeof(int), stream);

    row_norms_kernel<<<(N_S + K_C) / 4, 256, 0, stream>>>(S, M, snorm, mnorm);
    dist_argmin_kernel<<<(N_S / TM) * SPLIT, 256, 0, stream>>>(S, M, mnorm, pval, pidx, pm2);
    merge_bins_kernel<<<N_S / 256, 256, 0, stream>>>(pval, pidx, pm2, snorm, bins, out + KD,
                                                     flag_list, flag_count);
    cleanup_kernel<<<1024, 256, 0, stream>>>(S, M, snorm, mnorm, flag_list, flag_count,
                                             bins, out + KD);
    scatter_kernel<<<N_S / 4, 256, 0, stream>>>(S, bins, out, counts);
    finalize_kernel<<<KD / 256, 256, 0, stream>>>(M, W, counts, out);
  }
}

// Round 11
// 284.449 us; speedup vs baseline: 1.3802x; 1.3802x over previous
//
#include <hip/hip_runtime.h>
#include <hip/hip_bf16.h>
#include <math.h>
#include <float.h>

#define N_S   32768
#define K_C   2048
#define D_DIM 512
#define KD    (K_C * D_DIM)
#define MARGIN 0.75f     // hi*hi-only approx: >=7-sigma of error-difference (sd~0.10)
#define FB_MARGIN 0.02f  // fallback path (3-term split) margin

using s16x8 = __attribute__((ext_vector_type(8))) short;
using f32x4 = __attribute__((ext_vector_type(4))) float;

typedef const __attribute__((address_space(1))) unsigned int glb_u32_t;
typedef __attribute__((address_space(3))) unsigned int lds_u32_t;

__device__ __forceinline__ void gll16(const void* g, void* l) {
  __builtin_amdgcn_global_load_lds((glb_u32_t*)g, (lds_u32_t*)l, 16, 0, 0);
}

__device__ inline void cvt_hl(float x, ushort& hb, ushort& lb) {
  __hip_bfloat16 h = __float2bfloat16(x);
  hb = *reinterpret_cast<ushort*>(&h);
  float hf = __bfloat162float(h);
  __hip_bfloat16 l = __float2bfloat16(x - hf);
  lb = *reinterpret_cast<ushort*>(&l);
}

__device__ inline void top2_merge(float& a1, int& ai, float& a2, float b1, int bi, float b2) {
  if (b1 < a1 || (b1 == a1 && bi < ai)) { a2 = fminf(a1, b2); a1 = b1; ai = bi; }
  else { a2 = fminf(a2, b1); }
}

// ================================================================ FAST PATH

// Convert fp32 -> hi bf16 only, pre-tiled+swizzled; fused row norms.
__global__ void preconvert_kernel(const float* __restrict__ S, const float* __restrict__ M,
                                  ushort* __restrict__ Aq, ushort* __restrict__ Bq,
                                  float* __restrict__ snorm, float* __restrict__ mnorm) {
  int row = blockIdx.x * 4 + (threadIdx.x >> 6);
  int l   = threadIdx.x & 63;
  bool isS = row < N_S;
  int lr = isS ? row : row - N_S;
  const float* src = (isS ? S : M) + (size_t)lr * D_DIM + l * 8;
  float4 u0 = *(const float4*)(src);
  float4 u1 = *(const float4*)(src + 4);
  float x[8] = {u0.x, u0.y, u0.z, u0.w, u1.x, u1.y, u1.z, u1.w};
  s16x8 hv;
  float nrm = 0.f;
#pragma unroll
  for (int i = 0; i < 8; ++i) {
    nrm += x[i] * x[i];
    __hip_bfloat16 h = __float2bfloat16(x[i]);
    hv[i] = *reinterpret_cast<short*>(&h);
  }
  int r = lr & 127, tile = lr >> 7;
  int kc = l >> 3, slot = (l & 7) ^ (r & 7);
  ushort* dst = isS ? Aq : Bq;
  size_t base = ((size_t)(tile * 8 + kc) * 128 + r) * 64 + slot * 8;
  *(s16x8*)(dst + base) = hv;
  for (int off = 32; off; off >>= 1) nrm += __shfl_down(nrm, off);
  if (l == 0) { if (isS) snorm[lr] = nrm; else mnorm[lr] = nrm; }
}

// 128x128 tile hi*hi bf16 GEMM (-2*S.M approx) + fused per-row top-2 partials.
// (round-9 proven version: 122us)
__launch_bounds__(256, 3)
__global__ void gemm_top2_kernel(const ushort* __restrict__ Aq, const ushort* __restrict__ Bq,
                                 const float* __restrict__ mnorm,
                                 float* __restrict__ pval, int* __restrict__ pidx,
                                 float* __restrict__ pm2) {
  __shared__ __align__(16) ushort lA[128 * 64];
  __shared__ __align__(16) ushort lB[128 * 64];
  __shared__ float rv1[128 * 2], rv2[128 * 2];
  __shared__ int   ri1[128 * 2];
  const int t = threadIdx.x, lane = t & 63, wid = t >> 6;
  const int wr = wid >> 1, wc = wid & 1;
  const int lx = lane & 15, kg = lane >> 4;
  int bid = ((int)blockIdx.x & 7) * 512 + ((int)blockIdx.x >> 3);
  const int rt = bid >> 4, ct = bid & 15;

  f32x4 acc[4][4];
#pragma unroll
  for (int i = 0; i < 4; ++i)
#pragma unroll
    for (int j = 0; j < 4; ++j) { acc[i][j][0] = 0.f; acc[i][j][1] = 0.f; acc[i][j][2] = 0.f; acc[i][j][3] = 0.f; }

  for (int s = 0; s < 8; ++s) {
    const char* ga = (const char*)(Aq + ((size_t)(rt * 8 + s) << 13));
    const char* gb = (const char*)(Bq + ((size_t)(ct * 8 + s) << 13));
    __syncthreads();
#pragma unroll
    for (int q = 0; q < 4; ++q) {
      gll16(ga + wid * 1024 + lane * 16 + q * 4096, (char*)lA + wid * 1024 + q * 4096);
      gll16(gb + wid * 1024 + lane * 16 + q * 4096, (char*)lB + wid * 1024 + q * 4096);
    }
    __syncthreads();
#pragma unroll
    for (int kk = 0; kk < 2; ++kk) {
      s16x8 af[4], bf[4];
#pragma unroll
      for (int i = 0; i < 4; ++i) {
        int r = wr * 64 + i * 16 + lx;
        af[i] = *(const s16x8*)&lA[r * 64 + (((kk * 4 + kg) ^ (lx & 7)) * 8)];
      }
#pragma unroll
      for (int j = 0; j < 4; ++j) {
        int r = wc * 64 + j * 16 + lx;
        bf[j] = *(const s16x8*)&lB[r * 64 + (((kk * 4 + kg) ^ (lx & 7)) * 8)];
      }
#pragma unroll
      for (int i = 0; i < 4; ++i)
#pragma unroll
        for (int j = 0; j < 4; ++j)
          acc[i][j] = __builtin_amdgcn_mfma_f32_16x16x32_bf16(af[i], bf[j], acc[i][j], 0, 0, 0);
    }
  }

  float mn[4];
#pragma unroll
  for (int j = 0; j < 4; ++j) mn[j] = mnorm[ct * 128 + wc * 64 + j * 16 + lx];
#pragma unroll
  for (int i = 0; i < 4; ++i)
#pragma unroll
    for (int reg = 0; reg < 4; ++reg) {
      float v1 = FLT_MAX, v2 = FLT_MAX; int i1 = 0;
#pragma unroll
      for (int j = 0; j < 4; ++j) {
        float v = mn[j] - 2.f * acc[i][j][reg];
        int k = ct * 128 + wc * 64 + j * 16 + lx;
        if (v < v1) { v2 = v1; v1 = v; i1 = k; } else v2 = fminf(v2, v);
      }
#pragma unroll
      for (int msk = 1; msk < 16; msk <<= 1) {
        float o1 = __shfl_xor(v1, msk);
        int   oi = __shfl_xor(i1, msk);
        float o2 = __shfl_xor(v2, msk);
        top2_merge(v1, i1, v2, o1, oi, o2);
      }
      if (lx == 0) {
        int rowr = wr * 64 + i * 16 + kg * 4 + reg;
        rv1[rowr * 2 + wc] = v1; ri1[rowr * 2 + wc] = i1; rv2[rowr * 2 + wc] = v2;
      }
    }
  __syncthreads();
  if (t < 128) {
    float a1 = rv1[t * 2], a2 = rv2[t * 2]; int ai = ri1[t * 2];
    top2_merge(a1, ai, a2, rv1[t * 2 + 1], ri1[t * 2 + 1], rv2[t * 2 + 1]);
    size_t n = (size_t)rt * 128 + t;
    pval[n * 16 + ct] = a1;
    pidx[n * 16 + ct] = ai;
    pm2 [n * 16 + ct] = a2;
  }
}

// merge 16 col-tile partials; flag ambiguous; emit DENSE (sample,tile) rescue worklist
// via wave-aggregated atomics; count + inertia for sure rows.
__global__ void merge2_kernel(const float* __restrict__ pval, const int* __restrict__ pidx,
                              const float* __restrict__ pm2, const float* __restrict__ snorm,
                              int* __restrict__ bins, float* __restrict__ inertia,
                              int* __restrict__ counts,
                              int* __restrict__ flag_list, int* __restrict__ flag_count,
                              int* __restrict__ worklist, int* __restrict__ wl_count,
                              unsigned long long* __restrict__ keys) {
  int n = blockIdx.x * 256 + threadIdx.x;
  int lane = threadIdx.x & 63;
  float pv[16], p2[16]; int pi[16];
  const float4* pv4 = (const float4*)(pval + (size_t)n * 16);
  const float4* p24 = (const float4*)(pm2  + (size_t)n * 16);
  const int4*   pi4 = (const int4*)  (pidx + (size_t)n * 16);
#pragma unroll
  for (int q = 0; q < 4; ++q) {
    float4 a = pv4[q]; float4 b = p24[q]; int4 c = pi4[q];
    pv[q*4+0]=a.x; pv[q*4+1]=a.y; pv[q*4+2]=a.z; pv[q*4+3]=a.w;
    p2[q*4+0]=b.x; p2[q*4+1]=b.y; p2[q*4+2]=b.z; p2[q*4+3]=b.w;
    pi[q*4+0]=c.x; pi[q*4+1]=c.y; pi[q*4+2]=c.z; pi[q*4+3]=c.w;
  }
  float a1 = FLT_MAX, a2 = FLT_MAX; int ai = 0x7fffffff;
#pragma unroll
  for (int c = 0; c < 16; ++c)
    top2_merge(a1, ai, a2, pv[c], pi[c], p2[c]);
  bool flg = (a2 - a1 <= MARGIN);
  float r = 0.f;
  if (flg) {
    keys[n] = ~0ull;
  } else {
    bins[n] = ai;
    atomicAdd(&counts[ai], 1);
    r = sqrtf(fmaxf(snorm[n] + a1, 0.f));
  }
  // flag_list append (wave-aggregated)
  {
    unsigned long long mask = __ballot(flg);
    if (mask) {
      int leader = __ffsll((unsigned long long)mask) - 1;
      int base = 0;
      if (lane == leader) base = atomicAdd(flag_count, __popcll(mask));
      base = __shfl(base, leader);
      if (flg) flag_list[base + __popcll(mask & ((1ull << lane) - 1))] = n;
    }
  }
  // worklist append: 128-cluster tiles that can contain the exact winner
#pragma unroll
  for (int c = 0; c < 16; ++c) {
    bool want = flg && (pv[c] <= a1 + MARGIN);
    unsigned long long mask = __ballot(want);
    if (mask) {
      int leader = __ffsll((unsigned long long)mask) - 1;
      int base = 0;
      if (lane == leader) base = atomicAdd(wl_count, __popcll(mask));
      base = __shfl(base, leader);
      if (want) worklist[base + __popcll(mask & ((1ull << lane) - 1))] = (n << 4) | c;
    }
  }
  for (int off = 32; off; off >>= 1) r += __shfl_down(r, off);
  if (lane == 0) atomicAdd(inertia, r);
}

// dense-worklist exact fp32 rescue: ONE ITEM PER WAVE (4 per block) for full
// item concurrency; item = (sample, 128-cluster tile); coalesced L2-resident
// M reads; packed-u64 atomicMin argmin.
__launch_bounds__(256)
__global__ void cleanup_work_kernel(const float* __restrict__ S, const float* __restrict__ M,
                                    const float* __restrict__ mnorm,
                                    const int* __restrict__ worklist, const int* __restrict__ wl_count,
                                    unsigned long long* __restrict__ keys) {
  const int t = threadIdx.x, lane = t & 63, wv = t >> 6;
  const int items = *wl_count;
  for (int it = blockIdx.x * 4 + wv; it < items; it += gridDim.x * 4) {
    int wi = worklist[it];
    int n = wi >> 4, tile = wi & 15;
    const float4* sp = (const float4*)(S + (size_t)n * D_DIM + lane * 8);
    float4 s0 = sp[0], s1 = sp[1];
    int kb = tile * 128;
    unsigned long long bestkey = ~0ull;
    for (int ro = 0; ro < 16; ++ro) {
      float p[8];
#pragma unroll
      for (int rj = 0; rj < 8; ++rj) {
        const float4* mr = (const float4*)(M + (size_t)(kb + ro * 8 + rj) * D_DIM + lane * 8);
        float4 a = mr[0], b = mr[1];
        p[rj] = a.x*s0.x + a.y*s0.y + a.z*s0.z + a.w*s0.w
              + b.x*s1.x + b.y*s1.y + b.z*s1.z + b.w*s1.w;
      }
#pragma unroll
      for (int rj = 0; rj < 8; ++rj)
#pragma unroll
        for (int off = 1; off < 64; off <<= 1) p[rj] += __shfl_xor(p[rj], off);
#pragma unroll
      for (int rj = 0; rj < 8; ++rj) {
        int k = kb + ro * 8 + rj;
        float dist = mnorm[k] - 2.f * p[rj];
        unsigned u = __float_as_uint(dist);
        u = (u >> 31) ? ~u : (u | 0x80000000u);
        unsigned long long key = ((unsigned long long)u << 32) | (unsigned)k;
        bestkey = bestkey < key ? bestkey : key;
      }
    }
    if (lane == 0) atomicMin(keys + n, bestkey);
  }
}

__global__ void cleanup_resolve_kernel(const int* __restrict__ flag_list, const int* __restrict__ flag_count,
                                       const unsigned long long* __restrict__ keys,
                                       const float* __restrict__ snorm,
                                       int* __restrict__ bins, int* __restrict__ counts,
                                       float* __restrict__ inertia) {
  int cnt = *flag_count;
  int i = blockIdx.x * 256 + threadIdx.x;
  float r = 0.f;
  if (i < cnt) {
    int n = flag_list[i];
    unsigned long long key = keys[n];
    int k = (int)(unsigned)(key & 0xffffffffu);
    unsigned u = (unsigned)(key >> 32);
    u = (u >> 31) ? (u & 0x7fffffffu) : ~u;
    float dist = __uint_as_float(u);
    bins[n] = k;
    atomicAdd(&counts[k], 1);
    r = sqrtf(fmaxf(snorm[n] + dist, 0.f));
  }
  for (int off = 32; off; off >>= 1) r += __shfl_down(r, off);
  if ((threadIdx.x & 63) == 0) atomicAdd(inertia, r);
}

// exclusive prefix sum over 2048 counts — single wave, shfl scan (no barriers)
__global__ void prefix_kernel(const int* __restrict__ counts, int* __restrict__ cursor) {
  int l = threadIdx.x;               // 0..63
  int loc[32]; int s = 0;
#pragma unroll
  for (int i = 0; i < 32; ++i) { loc[i] = s; s += counts[l * 32 + i]; }
  int tot = s;
#pragma unroll
  for (int off = 1; off < 64; off <<= 1) {
    int v = __shfl_up(tot, off);
    if (l >= off) tot += v;
  }
  int base = tot - s;
#pragma unroll
  for (int i = 0; i < 32; ++i) cursor[l * 32 + i] = base + loc[i];
}

// bucket-fill: cluster-sorted sample list + per-slot cluster id
__global__ void fill_kernel(const int* __restrict__ bins, int* __restrict__ cursor,
                            int* __restrict__ bucket, int* __restrict__ bcl) {
  int n = blockIdx.x * 256 + threadIdx.x;
  int b = bins[n];
  int pos = atomicAdd(&cursor[b], 1);
  bucket[pos] = n;
  bcl[pos] = b;
}

// segment-scatter: each block owns a fixed 64-entry segment of the sorted bucket;
// register-accumulate runs of equal cluster, flush one atomicAdd per run.
__launch_bounds__(256)
__global__ void segscatter_kernel(const float* __restrict__ S, const int* __restrict__ bucket,
                                  const int* __restrict__ bcl, float* __restrict__ out) {
  __shared__ int sn[64], sk[64];
  const int t = threadIdx.x;
  const int i0 = blockIdx.x * 64;
  if (t < 64) { sn[t] = bucket[i0 + t]; sk[t] = bcl[i0 + t]; }
  __syncthreads();
  float a0 = 0.f, a1 = 0.f;
  int cur = sk[0];
  for (int i = 0; i < 64; ++i) {
    int k = sk[i];
    if (k != cur) {
      atomicAdd(&out[(size_t)cur * D_DIM + t], a0);
      atomicAdd(&out[(size_t)cur * D_DIM + t + 256], a1);
      a0 = 0.f; a1 = 0.f; cur = k;
    }
    const float* row = S + (size_t)sn[i] * D_DIM;
    a0 += row[t];
    a1 += row[t + 256];
  }
  atomicAdd(&out[(size_t)cur * D_DIM + t], a0);
  atomicAdd(&out[(size_t)cur * D_DIM + t + 256], a1);
}

// finalize: out currently holds cluster_sums; apply (sum + m*w)*alpha / keep-old rule
__global__ void finalize2_kernel(const float* __restrict__ M, const float* __restrict__ W,
                                 const int* __restrict__ counts, float* __restrict__ out) {
  int idx = blockIdx.x * 256 + threadIdx.x;
  int k = idx >> 9;
  int cnt = counts[k];
  float w = W[k];
  float nw = w + (float)cnt;
  float alpha = 1.f / ((nw == 0.f) ? 1.f : nw);
  float m = M[idx];
  float v = (out[idx] + m * w) * alpha;
  out[idx] = (cnt == 0) ? m : v;
}

// ============================================================ FALLBACK PATH (round-2)

#define TM    128
#define BK2   32
#define SPLIT 2
#define KPER  (K_C / SPLIT)
#define NKT   (KPER / TM)
#define NDT   (D_DIM / BK2)

__global__ void row_norms_kernel(const float* __restrict__ S, const float* __restrict__ M,
                                 float* __restrict__ snorm, float* __restrict__ mnorm) {
  int row  = blockIdx.x * 4 + (threadIdx.x >> 6);
  int lane = threadIdx.x & 63;
  if (row >= N_S + K_C) return;
  const float* src;
  float* dst;
  if (row < N_S) { src = S + (size_t)row * D_DIM; dst = snorm + row; }
  else { int r = row - N_S; src = M + (size_t)r * D_DIM; dst = mnorm + r; }
  float4 v0 = *(const float4*)(src + lane * 4);
  float4 v1 = *(const float4*)(src + 256 + lane * 4);
  float s = v0.x*v0.x + v0.y*v0.y + v0.z*v0.z + v0.w*v0.w
          + v1.x*v1.x + v1.y*v1.y + v1.z*v1.z + v1.w*v1.w;
  for (int off = 32; off; off >>= 1) s += __shfl_down(s, off);
  if (lane == 0) *dst = s;
}

__launch_bounds__(256)
__global__ void dist_argmin_kernel(const float* __restrict__ S, const float* __restrict__ M,
                                   const float* __restrict__ mnorm,
                                   float* __restrict__ pval, int* __restrict__ pidx,
                                   float* __restrict__ pm2) {
  __shared__ ushort tiles[2][4][TM * BK2];
  __shared__ float sm1[TM * 2];
  __shared__ float sm2[TM * 2];
  __shared__ int   si1[TM * 2];
  const int t    = threadIdx.x;
  const int lane = t & 63, wid = t >> 6;
  const int wr   = wid >> 1, wc = wid & 1;
  const int lx   = lane & 15, kg = lane >> 4;
  const int stile = blockIdx.x >> 1, split = blockIdx.x & 1;
  const int srow0 = stile * TM;
  const int kcol0 = split * KPER;
  for (int i = t; i < TM * 2; i += 256) { sm1[i] = FLT_MAX; sm2[i] = FLT_MAX; si1[i] = 0; }
  float4 av[4], bv[4];
#define LOADREGS(dtoff) do { \
    const float* Ag = S + (size_t)srow0 * D_DIM + (dtoff); \
    const float* Bg = M + (size_t)kbase * D_DIM + (dtoff); \
    _Pragma("unroll") \
    for (int q = 0; q < 4; ++q) { \
      int id = t + q * 256; int r_ = id >> 3, c_ = (id & 7) * 4; \
      av[q] = *(const float4*)(Ag + (size_t)r_ * D_DIM + c_); \
      bv[q] = *(const float4*)(Bg + (size_t)r_ * D_DIM + c_); \
    } } while (0)
#define WRITETILE(buf) do { \
    _Pragma("unroll") \
    for (int q = 0; q < 4; ++q) { \
      int id = t + q * 256; int r_ = id >> 3, c_ = (id & 7) * 4; \
      ushort4 h4, l4; \
      cvt_hl(av[q].x, h4.x, l4.x); cvt_hl(av[q].y, h4.y, l4.y); \
      cvt_hl(av[q].z, h4.z, l4.z); cvt_hl(av[q].w, h4.w, l4.w); \
      *(ushort4*)&tiles[buf][0][r_ * BK2 + c_] = h4; \
      *(ushort4*)&tiles[buf][1][r_ * BK2 + c_] = l4; \
      cvt_hl(bv[q].x, h4.x, l4.x); cvt_hl(bv[q].y, h4.y, l4.y); \
      cvt_hl(bv[q].z, h4.z, l4.z); cvt_hl(bv[q].w, h4.w, l4.w); \
      *(ushort4*)&tiles[buf][2][r_ * BK2 + c_] = h4; \
      *(ushort4*)&tiles[buf][3][r_ * BK2 + c_] = l4; \
    } } while (0)
  for (int kt = 0; kt < NKT; ++kt) {
    const int kbase = kcol0 + kt * TM;
    f32x4 acc[4][4];
#pragma unroll
    for (int i = 0; i < 4; ++i)
#pragma unroll
      for (int j = 0; j < 4; ++j) { acc[i][j][0] = 0.f; acc[i][j][1] = 0.f; acc[i][j][2] = 0.f; acc[i][j][3] = 0.f; }
    float mn[4];
#pragma unroll
    for (int ni = 0; ni < 4; ++ni) mn[ni] = mnorm[kbase + wc * 64 + ni * 16 + lx];
    LOADREGS(0);
    WRITETILE(0);
    __syncthreads();
    for (int di = 0; di < NDT; ++di) {
      const int cur = di & 1;
      if (di + 1 < NDT) LOADREGS((di + 1) * BK2);
      {
        s16x8 ah[4], al[4], bh[4], bl[4];
#pragma unroll
        for (int i = 0; i < 4; ++i) {
          ah[i] = *(const s16x8*)&tiles[cur][0][(wr * 64 + i * 16 + lx) * BK2 + kg * 8];
          al[i] = *(const s16x8*)&tiles[cur][1][(wr * 64 + i * 16 + lx) * BK2 + kg * 8];
          bh[i] = *(const s16x8*)&tiles[cur][2][(wc * 64 + i * 16 + lx) * BK2 + kg * 8];
          bl[i] = *(const s16x8*)&tiles[cur][3][(wc * 64 + i * 16 + lx) * BK2 + kg * 8];
        }
#pragma unroll
        for (int i = 0; i < 4; ++i)
#pragma unroll
          for (int j = 0; j < 4; ++j) {
            acc[i][j] = __builtin_amdgcn_mfma_f32_16x16x32_bf16(ah[i], bh[j], acc[i][j], 0, 0, 0);
            acc[i][j] = __builtin_amdgcn_mfma_f32_16x16x32_bf16(ah[i], bl[j], acc[i][j], 0, 0, 0);
            acc[i][j] = __builtin_amdgcn_mfma_f32_16x16x32_bf16(al[i], bh[j], acc[i][j], 0, 0, 0);
          }
      }
      if (di + 1 < NDT) { WRITETILE(cur ^ 1); __syncthreads(); }
    }
#pragma unroll
    for (int mi = 0; mi < 4; ++mi)
#pragma unroll
      for (int r = 0; r < 4; ++r) {
        float v1 = FLT_MAX, v2 = FLT_MAX; int i1 = 0;
#pragma unroll
        for (int ni = 0; ni < 4; ++ni) {
          float v = mn[ni] - 2.f * acc[mi][ni][r];
          int k = kbase + wc * 64 + ni * 16 + lx;
          if (v < v1) { v2 = v1; v1 = v; i1 = k; } else { v2 = fminf(v2, v); }
        }
#pragma unroll
        for (int msk = 1; msk < 16; msk <<= 1) {
          float o1 = __shfl_xor(v1, msk);
          int   oi = __shfl_xor(i1, msk);
          float o2 = __shfl_xor(v2, msk);
          top2_merge(v1, i1, v2, o1, oi, o2);
        }
        if (lx == 0) {
          int row = wr * 64 + mi * 16 + kg * 4 + r;
          int s = row * 2 + wc;
          float a1 = sm1[s], a2 = sm2[s]; int ai = si1[s];
          top2_merge(a1, ai, a2, v1, i1, v2);
          sm1[s] = a1; sm2[s] = a2; si1[s] = ai;
        }
      }
  }
  __syncthreads();
  if (t < TM) {
    float a1 = sm1[t * 2], a2 = sm2[t * 2]; int ai = si1[t * 2];
    top2_merge(a1, ai, a2, sm1[t * 2 + 1], si1[t * 2 + 1], sm2[t * 2 + 1]);
    int n = srow0 + t;
    pval[n * SPLIT + split] = a1;
    pidx[n * SPLIT + split] = ai;
    pm2[n * SPLIT + split]  = a2;
  }
#undef LOADREGS
#undef WRITETILE
}

__global__ void merge_bins_kernel(const float* __restrict__ pval, const int* __restrict__ pidx,
                                  const float* __restrict__ pm2, const float* __restrict__ snorm,
                                  int* __restrict__ bins, float* __restrict__ inertia,
                                  int* __restrict__ flag_list, int* __restrict__ flag_count) {
  int n = blockIdx.x * 256 + threadIdx.x;
  float a1 = pval[n * SPLIT], a2 = pm2[n * SPLIT]; int ai = pidx[n * SPLIT];
  top2_merge(a1, ai, a2, pval[n * SPLIT + 1], pidx[n * SPLIT + 1], pm2[n * SPLIT + 1]);
  float r = 0.f;
  if (a2 - a1 <= FB_MARGIN) {
    int idx = atomicAdd(flag_count, 1);
    flag_list[idx] = n;
  } else {
    bins[n] = ai;
    r = sqrtf(fmaxf(snorm[n] + a1, 0.f));
  }
  for (int off = 32; off; off >>= 1) r += __shfl_down(r, off);
  if ((threadIdx.x & 63) == 0) atomicAdd(inertia, r);
}

__launch_bounds__(256)
__global__ void cleanup_kernel(const float* __restrict__ S, const float* __restrict__ M,
                               const float* __restrict__ snorm, const float* __restrict__ mnorm,
                               const int* __restrict__ flag_list, const int* __restrict__ flag_count,
                               int* __restrict__ bins, float* __restrict__ inertia) {
  __shared__ float sS[D_DIM];
  __shared__ float wv[4];
  __shared__ int   wk[4];
  const int t = threadIdx.x, lane = t & 63, wid = t >> 6;
  const int cnt = *flag_count;
  for (int fi = blockIdx.x; fi < cnt; fi += gridDim.x) {
    int n = flag_list[fi];
    __syncthreads();
    for (int i = t; i < D_DIM; i += 256) sS[i] = S[(size_t)n * D_DIM + i];
    __syncthreads();
    float best = FLT_MAX; int bk = 0;
    for (int k = wid; k < K_C; k += 4) {
      const float* mr = M + (size_t)k * D_DIM;
      float4 m0 = *(const float4*)(mr + lane * 8);
      float4 m1 = *(const float4*)(mr + lane * 8 + 4);
      float4 s0 = *(const float4*)(sS + lane * 8);
      float4 s1 = *(const float4*)(sS + lane * 8 + 4);
      float p = m0.x*s0.x + m0.y*s0.y + m0.z*s0.z + m0.w*s0.w
              + m1.x*s1.x + m1.y*s1.y + m1.z*s1.z + m1.w*s1.w;
      for (int msk = 1; msk < 64; msk <<= 1) p += __shfl_xor(p, msk);
      float dist = mnorm[k] - 2.f * p;
      if (dist < best) { best = dist; bk = k; }
    }
    if (lane == 0) { wv[wid] = best; wk[wid] = bk; }
    __syncthreads();
    if (t == 0) {
      float b = wv[0]; int bi = wk[0];
      for (int w = 1; w < 4; ++w)
        if (wv[w] < b || (wv[w] == b && wk[w] < bi)) { b = wv[w]; bi = wk[w]; }
      bins[n] = bi;
      atomicAdd(inertia, sqrtf(fmaxf(snorm[n] + b, 0.f)));
    }
  }
}

__global__ void scatter_kernel(const float* __restrict__ S, const int* __restrict__ bins,
                               float* __restrict__ csum, float* __restrict__ counts) {
  int w    = (blockIdx.x * 256 + threadIdx.x) >> 6;
  int lane = threadIdx.x & 63;
  if (w >= N_S) return;
  int b = bins[w];
  const float* src = S + (size_t)w * D_DIM;
  float* dst = csum + (size_t)b * D_DIM;
#pragma unroll
  for (int c = 0; c < D_DIM; c += 64) atomicAdd(dst + c + lane, src[c + lane]);
  if (lane == 0) atomicAdd(counts + b, 1.0f);
}

__global__ void finalize_kernel(const float* __restrict__ M, const float* __restrict__ W,
                                const float* __restrict__ counts, float* __restrict__ out) {
  int idx = blockIdx.x * 256 + threadIdx.x;
  int k = idx >> 9;
  float cnt = counts[k];
  float w   = W[k];
  float nw  = w + cnt;
  float alpha = 1.f / ((nw == 0.f) ? 1.f : nw);
  float m = M[idx];
  float v = (out[idx] + m * w) * alpha;
  out[idx] = (cnt == 0.f) ? m : v;
}

// ================================================================= launcher

extern "C" void kernel_launch(void* const* d_in, const int* in_sizes, int n_in,
                              void* d_out, int out_size, void* d_ws, size_t ws_size,
                              hipStream_t stream) {
  const float* S = (const float*)d_in[0];
  const float* M = (const float*)d_in[1];
  const float* W = (const float*)d_in[2];
  float* out = (float*)d_out;
  char* ws = (char*)d_ws;

  const size_t oA  = 0;                                // A' hi 32 MiB
  const size_t oB  = oA  + (size_t)N_S * 1024;         // B' hi 2 MiB
  const size_t oPV = oB  + (size_t)K_C * 1024;         // pval [N][16]
  const size_t oPM = oPV + (size_t)N_S * 16 * 4;
  const size_t oPI = oPM + (size_t)N_S * 16 * 4;
  const size_t oSN = oPI + (size_t)N_S * 16 * 4;       // snorm
  const size_t oMN = oSN + (size_t)N_S * 4;            // mnorm
  const size_t oBI = oMN + (size_t)K_C * 4;            // bins
  const size_t oCN = oBI + (size_t)N_S * 4;            // counts (int)
  const size_t oCU = oCN + (size_t)K_C * 4;            // cursor
  const size_t oBK = oCU + (size_t)K_C * 4;            // bucket
  const size_t oBC = oBK + (size_t)N_S * 4;            // bcl
  const size_t oFC = oBC + (size_t)N_S * 4;            // flag_count + wl_count (64B)
  const size_t oFL = oFC + 64;                         // flag_list
  const size_t oKY = oFL + (size_t)N_S * 4;            // keys (u64)
  const size_t oWL = oKY + (size_t)N_S * 8;            // worklist (up to 16 per sample)
  const size_t NEED = oWL + (size_t)N_S * 16 * 4;

  if (ws_size >= NEED) {
    ushort* Aq = (ushort*)(ws + oA);
    ushort* Bq = (ushort*)(ws + oB);
    float* pval = (float*)(ws + oPV);
    float* pm2  = (float*)(ws + oPM);
    int*   pidx = (int*)(ws + oPI);
    float* snorm = (float*)(ws + oSN);
    float* mnorm = (float*)(ws + oMN);
    int* bins   = (int*)(ws + oBI);
    int* counts = (int*)(ws + oCN);
    int* cursor = (int*)(ws + oCU);
    int* bucket = (int*)(ws + oBK);
    int* bcl    = (int*)(ws + oBC);
    int* flag_count = (int*)(ws + oFC);
    int* wl_count   = flag_count + 1;
    int* flag_list  = (int*)(ws + oFL);
    unsigned long long* keys = (unsigned long long*)(ws + oKY);
    int* worklist = (int*)(ws + oWL);

    hipMemsetAsync(d_out, 0, (size_t)(KD + 1) * sizeof(float), stream);
    hipMemsetAsync(counts, 0, (size_t)K_C * 4, stream);
    hipMemsetAsync(flag_count, 0, 64, stream);   // zeroes flag_count AND wl_count

    preconvert_kernel<<<(N_S + K_C) / 4, 256, 0, stream>>>(S, M, Aq, Bq, snorm, mnorm);
    gemm_top2_kernel<<<4096, 256, 0, stream>>>(Aq, Bq, mnorm, pval, pidx, pm2);
    merge2_kernel<<<N_S / 256, 256, 0, stream>>>(pval, pidx, pm2, snorm, bins, out + KD,
                                                 counts, flag_list, flag_count,
                                                 worklist, wl_count, keys);
    cleanup_work_kernel<<<2048, 256, 0, stream>>>(S, M, mnorm, worklist, wl_count, keys);
    cleanup_resolve_kernel<<<N_S / 256, 256, 0, stream>>>(flag_list, flag_count, keys, snorm,
                                                          bins, counts, out + KD);
    prefix_kernel<<<1, 64, 0, stream>>>(counts, cursor);
    fill_kernel<<<N_S / 256, 256, 0, stream>>>(bins, cursor, bucket, bcl);
    segscatter_kernel<<<N_S / 64, 256, 0, stream>>>(S, bucket, bcl, out);
    finalize2_kernel<<<KD / 256, 256, 0, stream>>>(M, W, counts, out);
  } else {
    float* mnorm     = (float*)ws;
    float* snorm     = mnorm + K_C;
    int*   bins      = (int*)(snorm + N_S);
    float* counts    = (float*)(bins + N_S);
    float* pval      = counts + K_C;
    int*   pidx      = (int*)(pval + (size_t)N_S * 2);
    float* pm2       = (float*)(pidx + (size_t)N_S * 2);
    int*   flag_count= (int*)(pm2 + (size_t)N_S * 2);
    int*   flag_list = flag_count + 16;

    hipMemsetAsync(d_out, 0, (size_t)(KD + 1) * sizeof(float), stream);
    hipMemsetAsync(counts, 0, K_C * sizeof(float), stream);
    hipMemsetAsync(flag_count, 0, sizeof(int), stream);

    row_norms_kernel<<<(N_S + K_C) / 4, 256, 0, stream>>>(S, M, snorm, mnorm);
    dist_argmin_kernel<<<(N_S / TM) * SPLIT, 256, 0, stream>>>(S, M, mnorm, pval, pidx, pm2);
    merge_bins_kernel<<<N_S / 256, 256, 0, stream>>>(pval, pidx, pm2, snorm, bins, out + KD,
                                                     flag_list, flag_count);
    cleanup_kernel<<<1024, 256, 0, stream>>>(S, M, snorm, mnorm, flag_list, flag_count,
                                             bins, out + KD);
    scatter_kernel<<<N_S / 4, 256, 0, stream>>>(S, bins, out, counts);
    finalize_kernel<<<KD / 256, 256, 0, stream>>>(M, W, counts, out);
  }
}

// Round 12
// 255.739 us; speedup vs baseline: 1.5352x; 1.1123x over previous
//
#include <hip/hip_runtime.h>
#include <hip/hip_bf16.h>
#include <math.h>
#include <float.h>

#define N_S   32768
#define K_C   2048
#define D_DIM 512
#define KD    (K_C * D_DIM)
#define MARGIN 0.75f     // hi*hi-only approx: >=7-sigma of error-difference (sd~0.10)
#define FB_MARGIN 0.02f  // fallback path (3-term split) margin

using s16x8 = __attribute__((ext_vector_type(8))) short;
using f32x4 = __attribute__((ext_vector_type(4))) float;

typedef const __attribute__((address_space(1))) unsigned int glb_u32_t;
typedef __attribute__((address_space(3))) unsigned int lds_u32_t;

__device__ __forceinline__ void gll16(const void* g, void* l) {
  __builtin_amdgcn_global_load_lds((glb_u32_t*)g, (lds_u32_t*)l, 16, 0, 0);
}

__device__ inline void cvt_hl(float x, ushort& hb, ushort& lb) {
  __hip_bfloat16 h = __float2bfloat16(x);
  hb = *reinterpret_cast<ushort*>(&h);
  float hf = __bfloat162float(h);
  __hip_bfloat16 l = __float2bfloat16(x - hf);
  lb = *reinterpret_cast<ushort*>(&l);
}

__device__ inline void top2_merge(float& a1, int& ai, float& a2, float b1, int bi, float b2) {
  if (b1 < a1 || (b1 == a1 && bi < ai)) { a2 = fminf(a1, b2); a1 = b1; ai = bi; }
  else { a2 = fminf(a2, b1); }
}

// ================================================================ FAST PATH

// Convert fp32 -> hi bf16 only, pre-tiled+swizzled; fused row norms.
__global__ void preconvert_kernel(const float* __restrict__ S, const float* __restrict__ M,
                                  ushort* __restrict__ Aq, ushort* __restrict__ Bq,
                                  float* __restrict__ snorm, float* __restrict__ mnorm) {
  int row = blockIdx.x * 4 + (threadIdx.x >> 6);
  int l   = threadIdx.x & 63;
  bool isS = row < N_S;
  int lr = isS ? row : row - N_S;
  const float* src = (isS ? S : M) + (size_t)lr * D_DIM + l * 8;
  float4 u0 = *(const float4*)(src);
  float4 u1 = *(const float4*)(src + 4);
  float x[8] = {u0.x, u0.y, u0.z, u0.w, u1.x, u1.y, u1.z, u1.w};
  s16x8 hv;
  float nrm = 0.f;
#pragma unroll
  for (int i = 0; i < 8; ++i) {
    nrm += x[i] * x[i];
    __hip_bfloat16 h = __float2bfloat16(x[i]);
    hv[i] = *reinterpret_cast<short*>(&h);
  }
  int r = lr & 127, tile = lr >> 7;
  int kc = l >> 3, slot = (l & 7) ^ (r & 7);
  ushort* dst = isS ? Aq : Bq;
  size_t base = ((size_t)(tile * 8 + kc) * 128 + r) * 64 + slot * 8;
  *(s16x8*)(dst + base) = hv;
  for (int off = 32; off; off >>= 1) nrm += __shfl_down(nrm, off);
  if (l == 0) { if (isS) snorm[lr] = nrm; else mnorm[lr] = nrm; }
}

// 128x128 tile hi*hi bf16 GEMM (-2*S.M approx) + fused per-row top-2 partials.
// Epilogue: LDS-transpose two-phase reduce (no ds_bpermute chains).
__launch_bounds__(256, 3)
__global__ void gemm_top2_kernel(const ushort* __restrict__ Aq, const ushort* __restrict__ Bq,
                                 const float* __restrict__ mnorm,
                                 float* __restrict__ pval, int* __restrict__ pidx,
                                 float* __restrict__ pm2) {
  // union: main loop uses lA(16K)+lB(16K); epilogue reuses as e1/ei/e2 [128][33]
  __shared__ __align__(16) char smem[50688];
  ushort* lA = (ushort*)smem;
  ushort* lB = (ushort*)(smem + 16384);
  float*  e1 = (float*)smem;             // [128][33]
  int*    ei = (int*)(smem + 16896);
  float*  e2 = (float*)(smem + 33792);

  const int t = threadIdx.x, lane = t & 63, wid = t >> 6;
  const int wr = wid >> 1, wc = wid & 1;
  const int lx = lane & 15, kg = lane >> 4;
  int bid = ((int)blockIdx.x & 7) * 512 + ((int)blockIdx.x >> 3);
  const int rt = bid >> 4, ct = bid & 15;

  f32x4 acc[4][4];
#pragma unroll
  for (int i = 0; i < 4; ++i)
#pragma unroll
    for (int j = 0; j < 4; ++j) { acc[i][j][0] = 0.f; acc[i][j][1] = 0.f; acc[i][j][2] = 0.f; acc[i][j][3] = 0.f; }

  for (int s = 0; s < 8; ++s) {
    const char* ga = (const char*)(Aq + ((size_t)(rt * 8 + s) << 13));
    const char* gb = (const char*)(Bq + ((size_t)(ct * 8 + s) << 13));
    __syncthreads();
#pragma unroll
    for (int q = 0; q < 4; ++q) {
      gll16(ga + wid * 1024 + lane * 16 + q * 4096, (char*)lA + wid * 1024 + q * 4096);
      gll16(gb + wid * 1024 + lane * 16 + q * 4096, (char*)lB + wid * 1024 + q * 4096);
    }
    __syncthreads();
#pragma unroll
    for (int kk = 0; kk < 2; ++kk) {
      s16x8 af[4], bf[4];
#pragma unroll
      for (int i = 0; i < 4; ++i) {
        int r = wr * 64 + i * 16 + lx;
        af[i] = *(const s16x8*)&lA[r * 64 + (((kk * 4 + kg) ^ (lx & 7)) * 8)];
      }
#pragma unroll
      for (int j = 0; j < 4; ++j) {
        int r = wc * 64 + j * 16 + lx;
        bf[j] = *(const s16x8*)&lB[r * 64 + (((kk * 4 + kg) ^ (lx & 7)) * 8)];
      }
#pragma unroll
      for (int i = 0; i < 4; ++i)
#pragma unroll
        for (int j = 0; j < 4; ++j)
          acc[i][j] = __builtin_amdgcn_mfma_f32_16x16x32_bf16(af[i], bf[j], acc[i][j], 0, 0, 0);
    }
  }

  __syncthreads();                       // all lA/lB reads done; reuse as e1/ei/e2
  float mn[4];
#pragma unroll
  for (int j = 0; j < 4; ++j) mn[j] = mnorm[ct * 128 + wc * 64 + j * 16 + lx];
#pragma unroll
  for (int i = 0; i < 4; ++i)
#pragma unroll
    for (int reg = 0; reg < 4; ++reg) {
      float v1 = FLT_MAX, v2 = FLT_MAX; int i1 = 0;
#pragma unroll
      for (int j = 0; j < 4; ++j) {                 // j ascending => k ascending
        float v = mn[j] - 2.f * acc[i][j][reg];
        int k = ct * 128 + wc * 64 + j * 16 + lx;
        if (v < v1) { v2 = v1; v1 = v; i1 = k; } else v2 = fminf(v2, v);
      }
      int row = wr * 64 + i * 16 + kg * 4 + reg;
      int e = wc * 16 + lx;
      e1[row * 33 + e] = v1;
      ei[row * 33 + e] = i1;
      e2[row * 33 + e] = v2;
    }
  __syncthreads();
  if (t < 128) {
    float a1 = FLT_MAX, a2 = FLT_MAX; int ai = 0x7fffffff;
#pragma unroll
    for (int e = 0; e < 32; ++e)                    // e ascending => k ascending
      top2_merge(a1, ai, a2, e1[t * 33 + e], ei[t * 33 + e], e2[t * 33 + e]);
    size_t n = (size_t)rt * 128 + t;
    pval[n * 16 + ct] = a1;
    pidx[n * 16 + ct] = ai;
    pm2 [n * 16 + ct] = a2;
  }
}

// merge 16 col-tile partials; flag ambiguous; emit DENSE (sample,tile) rescue worklist
// via wave-aggregated atomics; count + inertia for sure rows.
__global__ void merge2_kernel(const float* __restrict__ pval, const int* __restrict__ pidx,
                              const float* __restrict__ pm2, const float* __restrict__ snorm,
                              int* __restrict__ bins, float* __restrict__ inertia,
                              int* __restrict__ counts,
                              int* __restrict__ flag_list, int* __restrict__ flag_count,
                              int* __restrict__ worklist, int* __restrict__ wl_count,
                              unsigned long long* __restrict__ keys) {
  int n = blockIdx.x * 256 + threadIdx.x;
  int lane = threadIdx.x & 63;
  float pv[16], p2[16]; int pi[16];
  const float4* pv4 = (const float4*)(pval + (size_t)n * 16);
  const float4* p24 = (const float4*)(pm2  + (size_t)n * 16);
  const int4*   pi4 = (const int4*)  (pidx + (size_t)n * 16);
#pragma unroll
  for (int q = 0; q < 4; ++q) {
    float4 a = pv4[q]; float4 b = p24[q]; int4 c = pi4[q];
    pv[q*4+0]=a.x; pv[q*4+1]=a.y; pv[q*4+2]=a.z; pv[q*4+3]=a.w;
    p2[q*4+0]=b.x; p2[q*4+1]=b.y; p2[q*4+2]=b.z; p2[q*4+3]=b.w;
    pi[q*4+0]=c.x; pi[q*4+1]=c.y; pi[q*4+2]=c.z; pi[q*4+3]=c.w;
  }
  float a1 = FLT_MAX, a2 = FLT_MAX; int ai = 0x7fffffff;
#pragma unroll
  for (int c = 0; c < 16; ++c)
    top2_merge(a1, ai, a2, pv[c], pi[c], p2[c]);
  bool flg = (a2 - a1 <= MARGIN);
  float r = 0.f;
  if (flg) {
    keys[n] = ~0ull;
  } else {
    bins[n] = ai;
    atomicAdd(&counts[ai], 1);
    r = sqrtf(fmaxf(snorm[n] + a1, 0.f));
  }
  // flag_list append (wave-aggregated)
  {
    unsigned long long mask = __ballot(flg);
    if (mask) {
      int leader = __ffsll((unsigned long long)mask) - 1;
      int base = 0;
      if (lane == leader) base = atomicAdd(flag_count, __popcll(mask));
      base = __shfl(base, leader);
      if (flg) flag_list[base + __popcll(mask & ((1ull << lane) - 1))] = n;
    }
  }
  // worklist append: 128-cluster tiles that can contain the exact winner
#pragma unroll
  for (int c = 0; c < 16; ++c) {
    bool want = flg && (pv[c] <= a1 + MARGIN);
    unsigned long long mask = __ballot(want);
    if (mask) {
      int leader = __ffsll((unsigned long long)mask) - 1;
      int base = 0;
      if (lane == leader) base = atomicAdd(wl_count, __popcll(mask));
      base = __shfl(base, leader);
      if (want) worklist[base + __popcll(mask & ((1ull << lane) - 1))] = (n << 4) | c;
    }
  }
  for (int off = 32; off; off >>= 1) r += __shfl_down(r, off);
  if (lane == 0) atomicAdd(inertia, r);
}

// dense-worklist exact fp32 rescue: ONE ITEM PER WAVE (4 per block);
// item = (sample, 128-cluster tile); coalesced L2-resident M reads;
// packed-u64 atomicMin argmin.
__launch_bounds__(256)
__global__ void cleanup_work_kernel(const float* __restrict__ S, const float* __restrict__ M,
                                    const float* __restrict__ mnorm,
                                    const int* __restrict__ worklist, const int* __restrict__ wl_count,
                                    unsigned long long* __restrict__ keys) {
  const int t = threadIdx.x, lane = t & 63, wv = t >> 6;
  const int items = *wl_count;
  for (int it = blockIdx.x * 4 + wv; it < items; it += gridDim.x * 4) {
    int wi = worklist[it];
    int n = wi >> 4, tile = wi & 15;
    const float4* sp = (const float4*)(S + (size_t)n * D_DIM + lane * 8);
    float4 s0 = sp[0], s1 = sp[1];
    int kb = tile * 128;
    unsigned long long bestkey = ~0ull;
    for (int ro = 0; ro < 16; ++ro) {
      float p[8];
#pragma unroll
      for (int rj = 0; rj < 8; ++rj) {
        const float4* mr = (const float4*)(M + (size_t)(kb + ro * 8 + rj) * D_DIM + lane * 8);
        float4 a = mr[0], b = mr[1];
        p[rj] = a.x*s0.x + a.y*s0.y + a.z*s0.z + a.w*s0.w
              + b.x*s1.x + b.y*s1.y + b.z*s1.z + b.w*s1.w;
      }
#pragma unroll
      for (int rj = 0; rj < 8; ++rj)
#pragma unroll
        for (int off = 1; off < 64; off <<= 1) p[rj] += __shfl_xor(p[rj], off);
#pragma unroll
      for (int rj = 0; rj < 8; ++rj) {
        int k = kb + ro * 8 + rj;
        float dist = mnorm[k] - 2.f * p[rj];
        unsigned u = __float_as_uint(dist);
        u = (u >> 31) ? ~u : (u | 0x80000000u);
        unsigned long long key = ((unsigned long long)u << 32) | (unsigned)k;
        bestkey = bestkey < key ? bestkey : key;
      }
    }
    if (lane == 0) atomicMin(keys + n, bestkey);
  }
}

// fused: resolve flagged winners (single block, grid-stride) + barrier +
// exclusive prefix scan over 2048 counts (first wave, shfl scan).
__launch_bounds__(256)
__global__ void resolve_prefix_kernel(const int* __restrict__ flag_list, const int* __restrict__ flag_count,
                                      const unsigned long long* __restrict__ keys,
                                      const float* __restrict__ snorm,
                                      int* __restrict__ bins, int* __restrict__ counts,
                                      float* __restrict__ inertia, int* __restrict__ cursor) {
  const int t = threadIdx.x;
  const int cnt = *flag_count;
  float r = 0.f;
  for (int i = t; i < cnt; i += 256) {
    int n = flag_list[i];
    unsigned long long key = keys[n];
    int k = (int)(unsigned)(key & 0xffffffffu);
    unsigned u = (unsigned)(key >> 32);
    u = (u >> 31) ? (u & 0x7fffffffu) : ~u;
    float dist = __uint_as_float(u);
    bins[n] = k;
    atomicAdd(&counts[k], 1);
    r += sqrtf(fmaxf(snorm[n] + dist, 0.f));
  }
  for (int off = 32; off; off >>= 1) r += __shfl_down(r, off);
  if ((t & 63) == 0) atomicAdd(inertia, r);
  __syncthreads();
  if (t < 64) {
    int loc[32]; int s = 0;
#pragma unroll
    for (int i = 0; i < 32; ++i) { loc[i] = s; s += counts[t * 32 + i]; }
    int tot = s;
#pragma unroll
    for (int off = 1; off < 64; off <<= 1) {
      int v = __shfl_up(tot, off);
      if (t >= off) tot += v;
    }
    int base = tot - s;
#pragma unroll
    for (int i = 0; i < 32; ++i) cursor[t * 32 + i] = base + loc[i];
  }
}

// bucket-fill: cluster-sorted sample list + per-slot cluster id
__global__ void fill_kernel(const int* __restrict__ bins, int* __restrict__ cursor,
                            int* __restrict__ bucket, int* __restrict__ bcl) {
  int n = blockIdx.x * 256 + threadIdx.x;
  int b = bins[n];
  int pos = atomicAdd(&cursor[b], 1);
  bucket[pos] = n;
  bcl[pos] = b;
}

// segment-scatter: each block owns a fixed 64-entry segment of the sorted bucket;
// register-accumulate runs of equal cluster, flush one atomicAdd per run.
__launch_bounds__(256)
__global__ void segscatter_kernel(const float* __restrict__ S, const int* __restrict__ bucket,
                                  const int* __restrict__ bcl, float* __restrict__ out) {
  __shared__ int sn[64], sk[64];
  const int t = threadIdx.x;
  const int i0 = blockIdx.x * 64;
  if (t < 64) { sn[t] = bucket[i0 + t]; sk[t] = bcl[i0 + t]; }
  __syncthreads();
  float a0 = 0.f, a1 = 0.f;
  int cur = sk[0];
  for (int i = 0; i < 64; ++i) {
    int k = sk[i];
    if (k != cur) {
      atomicAdd(&out[(size_t)cur * D_DIM + t], a0);
      atomicAdd(&out[(size_t)cur * D_DIM + t + 256], a1);
      a0 = 0.f; a1 = 0.f; cur = k;
    }
    const float* row = S + (size_t)sn[i] * D_DIM;
    a0 += row[t];
    a1 += row[t + 256];
  }
  atomicAdd(&out[(size_t)cur * D_DIM + t], a0);
  atomicAdd(&out[(size_t)cur * D_DIM + t + 256], a1);
}

// finalize: out currently holds cluster_sums; apply (sum + m*w)*alpha / keep-old rule
__global__ void finalize2_kernel(const float* __restrict__ M, const float* __restrict__ W,
                                 const int* __restrict__ counts, float* __restrict__ out) {
  int idx = blockIdx.x * 256 + threadIdx.x;
  int k = idx >> 9;
  int cnt = counts[k];
  float w = W[k];
  float nw = w + (float)cnt;
  float alpha = 1.f / ((nw == 0.f) ? 1.f : nw);
  float m = M[idx];
  float v = (out[idx] + m * w) * alpha;
  out[idx] = (cnt == 0) ? m : v;
}

// ============================================================ FALLBACK PATH (round-2)

#define TM    128
#define BK2   32
#define SPLIT 2
#define KPER  (K_C / SPLIT)
#define NKT   (KPER / TM)
#define NDT   (D_DIM / BK2)

__global__ void row_norms_kernel(const float* __restrict__ S, const float* __restrict__ M,
                                 float* __restrict__ snorm, float* __restrict__ mnorm) {
  int row  = blockIdx.x * 4 + (threadIdx.x >> 6);
  int lane = threadIdx.x & 63;
  if (row >= N_S + K_C) return;
  const float* src;
  float* dst;
  if (row < N_S) { src = S + (size_t)row * D_DIM; dst = snorm + row; }
  else { int r = row - N_S; src = M + (size_t)r * D_DIM; dst = mnorm + r; }
  float4 v0 = *(const float4*)(src + lane * 4);
  float4 v1 = *(const float4*)(src + 256 + lane * 4);
  float s = v0.x*v0.x + v0.y*v0.y + v0.z*v0.z + v0.w*v0.w
          + v1.x*v1.x + v1.y*v1.y + v1.z*v1.z + v1.w*v1.w;
  for (int off = 32; off; off >>= 1) s += __shfl_down(s, off);
  if (lane == 0) *dst = s;
}

__launch_bounds__(256)
__global__ void dist_argmin_kernel(const float* __restrict__ S, const float* __restrict__ M,
                                   const float* __restrict__ mnorm,
                                   float* __restrict__ pval, int* __restrict__ pidx,
                                   float* __restrict__ pm2) {
  __shared__ ushort tiles[2][4][TM * BK2];
  __shared__ float sm1[TM * 2];
  __shared__ float sm2[TM * 2];
  __shared__ int   si1[TM * 2];
  const int t    = threadIdx.x;
  const int lane = t & 63, wid = t >> 6;
  const int wr   = wid >> 1, wc = wid & 1;
  const int lx   = lane & 15, kg = lane >> 4;
  const int stile = blockIdx.x >> 1, split = blockIdx.x & 1;
  const int srow0 = stile * TM;
  const int kcol0 = split * KPER;
  for (int i = t; i < TM * 2; i += 256) { sm1[i] = FLT_MAX; sm2[i] = FLT_MAX; si1[i] = 0; }
  float4 av[4], bv[4];
#define LOADREGS(dtoff) do { \
    const float* Ag = S + (size_t)srow0 * D_DIM + (dtoff); \
    const float* Bg = M + (size_t)kbase * D_DIM + (dtoff); \
    _Pragma("unroll") \
    for (int q = 0; q < 4; ++q) { \
      int id = t + q * 256; int r_ = id >> 3, c_ = (id & 7) * 4; \
      av[q] = *(const float4*)(Ag + (size_t)r_ * D_DIM + c_); \
      bv[q] = *(const float4*)(Bg + (size_t)r_ * D_DIM + c_); \
    } } while (0)
#define WRITETILE(buf) do { \
    _Pragma("unroll") \
    for (int q = 0; q < 4; ++q) { \
      int id = t + q * 256; int r_ = id >> 3, c_ = (id & 7) * 4; \
      ushort4 h4, l4; \
      cvt_hl(av[q].x, h4.x, l4.x); cvt_hl(av[q].y, h4.y, l4.y); \
      cvt_hl(av[q].z, h4.z, l4.z); cvt_hl(av[q].w, h4.w, l4.w); \
      *(ushort4*)&tiles[buf][0][r_ * BK2 + c_] = h4; \
      *(ushort4*)&tiles[buf][1][r_ * BK2 + c_] = l4; \
      cvt_hl(bv[q].x, h4.x, l4.x); cvt_hl(bv[q].y, h4.y, l4.y); \
      cvt_hl(bv[q].z, h4.z, l4.z); cvt_hl(bv[q].w, h4.w, l4.w); \
      *(ushort4*)&tiles[buf][2][r_ * BK2 + c_] = h4; \
      *(ushort4*)&tiles[buf][3][r_ * BK2 + c_] = l4; \
    } } while (0)
  for (int kt = 0; kt < NKT; ++kt) {
    const int kbase = kcol0 + kt * TM;
    f32x4 acc[4][4];
#pragma unroll
    for (int i = 0; i < 4; ++i)
#pragma unroll
      for (int j = 0; j < 4; ++j) { acc[i][j][0] = 0.f; acc[i][j][1] = 0.f; acc[i][j][2] = 0.f; acc[i][j][3] = 0.f; }
    float mn[4];
#pragma unroll
    for (int ni = 0; ni < 4; ++ni) mn[ni] = mnorm[kbase + wc * 64 + ni * 16 + lx];
    LOADREGS(0);
    WRITETILE(0);
    __syncthreads();
    for (int di = 0; di < NDT; ++di) {
      const int cur = di & 1;
      if (di + 1 < NDT) LOADREGS((di + 1) * BK2);
      {
        s16x8 ah[4], al[4], bh[4], bl[4];
#pragma unroll
        for (int i = 0; i < 4; ++i) {
          ah[i] = *(const s16x8*)&tiles[cur][0][(wr * 64 + i * 16 + lx) * BK2 + kg * 8];
          al[i] = *(const s16x8*)&tiles[cur][1][(wr * 64 + i * 16 + lx) * BK2 + kg * 8];
          bh[i] = *(const s16x8*)&tiles[cur][2][(wc * 64 + i * 16 + lx) * BK2 + kg * 8];
          bl[i] = *(const s16x8*)&tiles[cur][3][(wc * 64 + i * 16 + lx) * BK2 + kg * 8];
        }
#pragma unroll
        for (int i = 0; i < 4; ++i)
#pragma unroll
          for (int j = 0; j < 4; ++j) {
            acc[i][j] = __builtin_amdgcn_mfma_f32_16x16x32_bf16(ah[i], bh[j], acc[i][j], 0, 0, 0);
            acc[i][j] = __builtin_amdgcn_mfma_f32_16x16x32_bf16(ah[i], bl[j], acc[i][j], 0, 0, 0);
            acc[i][j] = __builtin_amdgcn_mfma_f32_16x16x32_bf16(al[i], bh[j], acc[i][j], 0, 0, 0);
          }
      }
      if (di + 1 < NDT) { WRITETILE(cur ^ 1); __syncthreads(); }
    }
#pragma unroll
    for (int mi = 0; mi < 4; ++mi)
#pragma unroll
      for (int r = 0; r < 4; ++r) {
        float v1 = FLT_MAX, v2 = FLT_MAX; int i1 = 0;
#pragma unroll
        for (int ni = 0; ni < 4; ++ni) {
          float v = mn[ni] - 2.f * acc[mi][ni][r];
          int k = kbase + wc * 64 + ni * 16 + lx;
          if (v < v1) { v2 = v1; v1 = v; i1 = k; } else { v2 = fminf(v2, v); }
        }
#pragma unroll
        for (int msk = 1; msk < 16; msk <<= 1) {
          float o1 = __shfl_xor(v1, msk);
          int   oi = __shfl_xor(i1, msk);
          float o2 = __shfl_xor(v2, msk);
          top2_merge(v1, i1, v2, o1, oi, o2);
        }
        if (lx == 0) {
          int row = wr * 64 + mi * 16 + kg * 4 + r;
          int s = row * 2 + wc;
          float a1 = sm1[s], a2 = sm2[s]; int ai = si1[s];
          top2_merge(a1, ai, a2, v1, i1, v2);
          sm1[s] = a1; sm2[s] = a2; si1[s] = ai;
        }
      }
  }
  __syncthreads();
  if (t < TM) {
    float a1 = sm1[t * 2], a2 = sm2[t * 2]; int ai = si1[t * 2];
    top2_merge(a1, ai, a2, sm1[t * 2 + 1], si1[t * 2 + 1], sm2[t * 2 + 1]);
    int n = srow0 + t;
    pval[n * SPLIT + split] = a1;
    pidx[n * SPLIT + split] = ai;
    pm2[n * SPLIT + split]  = a2;
  }
#undef LOADREGS
#undef WRITETILE
}

__global__ void merge_bins_kernel(const float* __restrict__ pval, const int* __restrict__ pidx,
                                  const float* __restrict__ pm2, const float* __restrict__ snorm,
                                  int* __restrict__ bins, float* __restrict__ inertia,
                                  int* __restrict__ flag_list, int* __restrict__ flag_count) {
  int n = blockIdx.x * 256 + threadIdx.x;
  float a1 = pval[n * SPLIT], a2 = pm2[n * SPLIT]; int ai = pidx[n * SPLIT];
  top2_merge(a1, ai, a2, pval[n * SPLIT + 1], pidx[n * SPLIT + 1], pm2[n * SPLIT + 1]);
  float r = 0.f;
  if (a2 - a1 <= FB_MARGIN) {
    int idx = atomicAdd(flag_count, 1);
    flag_list[idx] = n;
  } else {
    bins[n] = ai;
    r = sqrtf(fmaxf(snorm[n] + a1, 0.f));
  }
  for (int off = 32; off; off >>= 1) r += __shfl_down(r, off);
  if ((threadIdx.x & 63) == 0) atomicAdd(inertia, r);
}

__launch_bounds__(256)
__global__ void cleanup_kernel(const float* __restrict__ S, const float* __restrict__ M,
                               const float* __restrict__ snorm, const float* __restrict__ mnorm,
                               const int* __restrict__ flag_list, const int* __restrict__ flag_count,
                               int* __restrict__ bins, float* __restrict__ inertia) {
  __shared__ float sS[D_DIM];
  __shared__ float wv[4];
  __shared__ int   wk[4];
  const int t = threadIdx.x, lane = t & 63, wid = t >> 6;
  const int cnt = *flag_count;
  for (int fi = blockIdx.x; fi < cnt; fi += gridDim.x) {
    int n = flag_list[fi];
    __syncthreads();
    for (int i = t; i < D_DIM; i += 256) sS[i] = S[(size_t)n * D_DIM + i];
    __syncthreads();
    float best = FLT_MAX; int bk = 0;
    for (int k = wid; k < K_C; k += 4) {
      const float* mr = M + (size_t)k * D_DIM;
      float4 m0 = *(const float4*)(mr + lane * 8);
      float4 m1 = *(const float4*)(mr + lane * 8 + 4);
      float4 s0 = *(const float4*)(sS + lane * 8);
      float4 s1 = *(const float4*)(sS + lane * 8 + 4);
      float p = m0.x*s0.x + m0.y*s0.y + m0.z*s0.z + m0.w*s0.w
              + m1.x*s1.x + m1.y*s1.y + m1.z*s1.z + m1.w*s1.w;
      for (int msk = 1; msk < 64; msk <<= 1) p += __shfl_xor(p, msk);
      float dist = mnorm[k] - 2.f * p;
      if (dist < best) { best = dist; bk = k; }
    }
    if (lane == 0) { wv[wid] = best; wk[wid] = bk; }
    __syncthreads();
    if (t == 0) {
      float b = wv[0]; int bi = wk[0];
      for (int w = 1; w < 4; ++w)
        if (wv[w] < b || (wv[w] == b && wk[w] < bi)) { b = wv[w]; bi = wk[w]; }
      bins[n] = bi;
      atomicAdd(inertia, sqrtf(fmaxf(snorm[n] + b, 0.f)));
    }
  }
}

__global__ void scatter_kernel(const float* __restrict__ S, const int* __restrict__ bins,
                               float* __restrict__ csum, float* __restrict__ counts) {
  int w    = (blockIdx.x * 256 + threadIdx.x) >> 6;
  int lane = threadIdx.x & 63;
  if (w >= N_S) return;
  int b = bins[w];
  const float* src = S + (size_t)w * D_DIM;
  float* dst = csum + (size_t)b * D_DIM;
#pragma unroll
  for (int c = 0; c < D_DIM; c += 64) atomicAdd(dst + c + lane, src[c + lane]);
  if (lane == 0) atomicAdd(counts + b, 1.0f);
}

__global__ void finalize_kernel(const float* __restrict__ M, const float* __restrict__ W,
                                const float* __restrict__ counts, float* __restrict__ out) {
  int idx = blockIdx.x * 256 + threadIdx.x;
  int k = idx >> 9;
  float cnt = counts[k];
  float w   = W[k];
  float nw  = w + cnt;
  float alpha = 1.f / ((nw == 0.f) ? 1.f : nw);
  float m = M[idx];
  float v = (out[idx] + m * w) * alpha;
  out[idx] = (cnt == 0.f) ? m : v;
}

// ================================================================= launcher

extern "C" void kernel_launch(void* const* d_in, const int* in_sizes, int n_in,
                              void* d_out, int out_size, void* d_ws, size_t ws_size,
                              hipStream_t stream) {
  const float* S = (const float*)d_in[0];
  const float* M = (const float*)d_in[1];
  const float* W = (const float*)d_in[2];
  float* out = (float*)d_out;
  char* ws = (char*)d_ws;

  const size_t oA  = 0;                                // A' hi 32 MiB
  const size_t oB  = oA  + (size_t)N_S * 1024;         // B' hi 2 MiB
  const size_t oPV = oB  + (size_t)K_C * 1024;         // pval [N][16]
  const size_t oPM = oPV + (size_t)N_S * 16 * 4;
  const size_t oPI = oPM + (size_t)N_S * 16 * 4;
  const size_t oSN = oPI + (size_t)N_S * 16 * 4;       // snorm
  const size_t oMN = oSN + (size_t)N_S * 4;            // mnorm
  const size_t oBI = oMN + (size_t)K_C * 4;            // bins
  const size_t oCU = oBI + (size_t)N_S * 4;            // cursor
  const size_t oBK = oCU + (size_t)K_C * 4;            // bucket
  const size_t oBC = oBK + (size_t)N_S * 4;            // bcl
  const size_t oFC = oBC + (size_t)N_S * 4;            // flag_count + wl_count (64B)
  const size_t oCN = oFC + 64;                         // counts 8KB (adjacent: one memset)
  const size_t oFL = oCN + (size_t)K_C * 4;            // flag_list
  const size_t oKY = oFL + (size_t)N_S * 4;            // keys (u64)
  const size_t oWL = oKY + (size_t)N_S * 8;            // worklist (up to 16 per sample)
  const size_t NEED = oWL + (size_t)N_S * 16 * 4;

  if (ws_size >= NEED) {
    ushort* Aq = (ushort*)(ws + oA);
    ushort* Bq = (ushort*)(ws + oB);
    float* pval = (float*)(ws + oPV);
    float* pm2  = (float*)(ws + oPM);
    int*   pidx = (int*)(ws + oPI);
    float* snorm = (float*)(ws + oSN);
    float* mnorm = (float*)(ws + oMN);
    int* bins   = (int*)(ws + oBI);
    int* cursor = (int*)(ws + oCU);
    int* bucket = (int*)(ws + oBK);
    int* bcl    = (int*)(ws + oBC);
    int* flag_count = (int*)(ws + oFC);
    int* wl_count   = flag_count + 1;
    int* counts = (int*)(ws + oCN);
    int* flag_list  = (int*)(ws + oFL);
    unsigned long long* keys = (unsigned long long*)(ws + oKY);
    int* worklist = (int*)(ws + oWL);

    hipMemsetAsync(d_out, 0, (size_t)(KD + 1) * sizeof(float), stream);
    hipMemsetAsync(flag_count, 0, 64 + (size_t)K_C * 4, stream);  // flags + counts

    preconvert_kernel<<<(N_S + K_C) / 4, 256, 0, stream>>>(S, M, Aq, Bq, snorm, mnorm);
    gemm_top2_kernel<<<4096, 256, 0, stream>>>(Aq, Bq, mnorm, pval, pidx, pm2);
    merge2_kernel<<<N_S / 256, 256, 0, stream>>>(pval, pidx, pm2, snorm, bins, out + KD,
                                                 counts, flag_list, flag_count,
                                                 worklist, wl_count, keys);
    cleanup_work_kernel<<<2048, 256, 0, stream>>>(S, M, mnorm, worklist, wl_count, keys);
    resolve_prefix_kernel<<<1, 256, 0, stream>>>(flag_list, flag_count, keys, snorm,
                                                 bins, counts, out + KD, cursor);
    fill_kernel<<<N_S / 256, 256, 0, stream>>>(bins, cursor, bucket, bcl);
    segscatter_kernel<<<N_S / 64, 256, 0, stream>>>(S, bucket, bcl, out);
    finalize2_kernel<<<KD / 256, 256, 0, stream>>>(M, W, counts, out);
  } else {
    float* mnorm     = (float*)ws;
    float* snorm     = mnorm + K_C;
    int*   bins      = (int*)(snorm + N_S);
    float* counts    = (float*)(bins + N_S);
    float* pval      = counts + K_C;
    int*   pidx      = (int*)(pval + (size_t)N_S * 2);
    float* pm2       = (float*)(pidx + (size_t)N_S * 2);
    int*   flag_count= (int*)(pm2 + (size_t)N_S * 2);
    int*   flag_list = flag_count + 16;

    hipMemsetAsync(d_out, 0, (size_t)(KD + 1) * sizeof(float), stream);
    hipMemsetAsync(counts, 0, K_C * sizeof(float), stream);
    hipMemsetAsync(flag_count, 0, sizeof(int), stream);

    row_norms_kernel<<<(N_S + K_C) / 4, 256, 0, stream>>>(S, M, snorm, mnorm);
    dist_argmin_kernel<<<(N_S / TM) * SPLIT, 256, 0, stream>>>(S, M, mnorm, pval, pidx, pm2);
    merge_bins_kernel<<<N_S / 256, 256, 0, stream>>>(pval, pidx, pm2, snorm, bins, out + KD,
                                                     flag_list, flag_count);
    cleanup_kernel<<<1024, 256, 0, stream>>>(S, M, snorm, mnorm, flag_list, flag_count,
                                             bins, out + KD);
    scatter_kernel<<<N_S / 4, 256, 0, stream>>>(S, bins, out, counts);
    finalize_kernel<<<KD / 256, 256, 0, stream>>>(M, W, counts, out);
  }
}

// Round 13
// 230.844 us; speedup vs baseline: 1.7007x; 1.1078x over previous
//
#include <hip/hip_runtime.h>
#include <hip/hip_bf16.h>
#include <math.h>
#include <float.h>

#define N_S   32768
#define K_C   2048
#define D_DIM 512
#define KD    (K_C * D_DIM)
#define MARGIN 0.6f      // hi*hi-only approx: ~12-sigma of error-difference (sd~0.05)
#define FB_MARGIN 0.02f  // fallback path (3-term split) margin

using s16x8 = __attribute__((ext_vector_type(8))) short;
using f32x4 = __attribute__((ext_vector_type(4))) float;

typedef const __attribute__((address_space(1))) unsigned int glb_u32_t;
typedef __attribute__((address_space(3))) unsigned int lds_u32_t;

__device__ __forceinline__ void gll16(const void* g, void* l) {
  __builtin_amdgcn_global_load_lds((glb_u32_t*)g, (lds_u32_t*)l, 16, 0, 0);
}

__device__ inline void cvt_hl(float x, ushort& hb, ushort& lb) {
  __hip_bfloat16 h = __float2bfloat16(x);
  hb = *reinterpret_cast<ushort*>(&h);
  float hf = __bfloat162float(h);
  __hip_bfloat16 l = __float2bfloat16(x - hf);
  lb = *reinterpret_cast<ushort*>(&l);
}

__device__ inline void top2_merge(float& a1, int& ai, float& a2, float b1, int bi, float b2) {
  if (b1 < a1 || (b1 == a1 && bi < ai)) { a2 = fminf(a1, b2); a1 = b1; ai = bi; }
  else { a2 = fminf(a2, b1); }
}

// ================================================================ FAST PATH

// Convert fp32 -> hi bf16 only, pre-tiled+swizzled; fused row norms.
__global__ void preconvert_kernel(const float* __restrict__ S, const float* __restrict__ M,
                                  ushort* __restrict__ Aq, ushort* __restrict__ Bq,
                                  float* __restrict__ snorm, float* __restrict__ mnorm) {
  int row = blockIdx.x * 4 + (threadIdx.x >> 6);
  int l   = threadIdx.x & 63;
  bool isS = row < N_S;
  int lr = isS ? row : row - N_S;
  const float* src = (isS ? S : M) + (size_t)lr * D_DIM + l * 8;
  float4 u0 = *(const float4*)(src);
  float4 u1 = *(const float4*)(src + 4);
  float x[8] = {u0.x, u0.y, u0.z, u0.w, u1.x, u1.y, u1.z, u1.w};
  s16x8 hv;
  float nrm = 0.f;
#pragma unroll
  for (int i = 0; i < 8; ++i) {
    nrm += x[i] * x[i];
    __hip_bfloat16 h = __float2bfloat16(x[i]);
    hv[i] = *reinterpret_cast<short*>(&h);
  }
  int r = lr & 127, tile = lr >> 7;
  int kc = l >> 3, slot = (l & 7) ^ (r & 7);
  ushort* dst = isS ? Aq : Bq;
  size_t base = ((size_t)(tile * 8 + kc) * 128 + r) * 64 + slot * 8;
  *(s16x8*)(dst + base) = hv;
  for (int off = 32; off; off >>= 1) nrm += __shfl_down(nrm, off);
  if (l == 0) { if (isS) snorm[lr] = nrm; else mnorm[lr] = nrm; }
}

// 128x128 tile hi*hi bf16 GEMM (-2*S.M approx) + fused per-row top-2 partials.
// Epilogue: LDS-transpose two-phase reduce (stride 34: conflict-free).
__launch_bounds__(256, 3)
__global__ void gemm_top2_kernel(const ushort* __restrict__ Aq, const ushort* __restrict__ Bq,
                                 const float* __restrict__ mnorm,
                                 float* __restrict__ pval, int* __restrict__ pidx,
                                 float* __restrict__ pm2) {
  // union: main loop uses lA(16K)+lB(16K); epilogue reuses as e1/ei/e2 [128][34]
  __shared__ __align__(16) char smem[52224];
  ushort* lA = (ushort*)smem;
  ushort* lB = (ushort*)(smem + 16384);
  float*  e1 = (float*)smem;             // [128][34]
  int*    ei = (int*)(smem + 17408);
  float*  e2 = (float*)(smem + 34816);

  const int t = threadIdx.x, lane = t & 63, wid = t >> 6;
  const int wr = wid >> 1, wc = wid & 1;
  const int lx = lane & 15, kg = lane >> 4;
  int bid = ((int)blockIdx.x & 7) * 512 + ((int)blockIdx.x >> 3);
  const int rt = bid >> 4, ct = bid & 15;

  f32x4 acc[4][4];
#pragma unroll
  for (int i = 0; i < 4; ++i)
#pragma unroll
    for (int j = 0; j < 4; ++j) { acc[i][j][0] = 0.f; acc[i][j][1] = 0.f; acc[i][j][2] = 0.f; acc[i][j][3] = 0.f; }

  for (int s = 0; s < 8; ++s) {
    const char* ga = (const char*)(Aq + ((size_t)(rt * 8 + s) << 13));
    const char* gb = (const char*)(Bq + ((size_t)(ct * 8 + s) << 13));
    __syncthreads();
#pragma unroll
    for (int q = 0; q < 4; ++q) {
      gll16(ga + wid * 1024 + lane * 16 + q * 4096, (char*)lA + wid * 1024 + q * 4096);
      gll16(gb + wid * 1024 + lane * 16 + q * 4096, (char*)lB + wid * 1024 + q * 4096);
    }
    __syncthreads();
#pragma unroll
    for (int kk = 0; kk < 2; ++kk) {
      s16x8 af[4], bf[4];
#pragma unroll
      for (int i = 0; i < 4; ++i) {
        int r = wr * 64 + i * 16 + lx;
        af[i] = *(const s16x8*)&lA[r * 64 + (((kk * 4 + kg) ^ (lx & 7)) * 8)];
      }
#pragma unroll
      for (int j = 0; j < 4; ++j) {
        int r = wc * 64 + j * 16 + lx;
        bf[j] = *(const s16x8*)&lB[r * 64 + (((kk * 4 + kg) ^ (lx & 7)) * 8)];
      }
#pragma unroll
      for (int i = 0; i < 4; ++i)
#pragma unroll
        for (int j = 0; j < 4; ++j)
          acc[i][j] = __builtin_amdgcn_mfma_f32_16x16x32_bf16(af[i], bf[j], acc[i][j], 0, 0, 0);
    }
  }

  __syncthreads();                       // all lA/lB reads done; reuse as e1/ei/e2
  float mn[4];
#pragma unroll
  for (int j = 0; j < 4; ++j) mn[j] = mnorm[ct * 128 + wc * 64 + j * 16 + lx];
#pragma unroll
  for (int i = 0; i < 4; ++i)
#pragma unroll
    for (int reg = 0; reg < 4; ++reg) {
      float v1 = FLT_MAX, v2 = FLT_MAX; int i1 = 0;
#pragma unroll
      for (int j = 0; j < 4; ++j) {                 // j ascending => k ascending
        float v = mn[j] - 2.f * acc[i][j][reg];
        int k = ct * 128 + wc * 64 + j * 16 + lx;
        if (v < v1) { v2 = v1; v1 = v; i1 = k; } else v2 = fminf(v2, v);
      }
      int row = wr * 64 + i * 16 + kg * 4 + reg;
      int e = wc * 16 + lx;
      e1[row * 34 + e] = v1;
      ei[row * 34 + e] = i1;
      e2[row * 34 + e] = v2;
    }
  __syncthreads();
  if (t < 128) {
    float a1 = FLT_MAX, a2 = FLT_MAX; int ai = 0x7fffffff;
#pragma unroll
    for (int e = 0; e < 32; ++e)                    // e ascending => k ascending
      top2_merge(a1, ai, a2, e1[t * 34 + e], ei[t * 34 + e], e2[t * 34 + e]);
    size_t n = (size_t)rt * 128 + t;
    pval[n * 16 + ct] = a1;
    pidx[n * 16 + ct] = ai;
    pm2 [n * 16 + ct] = a2;
  }
}

// merge 16 col-tile partials; flag ambiguous; emit DENSE (sample,tile) rescue worklist
// via wave-aggregated atomics; count + inertia for sure rows.
__global__ void merge2_kernel(const float* __restrict__ pval, const int* __restrict__ pidx,
                              const float* __restrict__ pm2, const float* __restrict__ snorm,
                              int* __restrict__ bins, float* __restrict__ inertia,
                              int* __restrict__ counts,
                              int* __restrict__ flag_list, int* __restrict__ flag_count,
                              int* __restrict__ worklist, int* __restrict__ wl_count,
                              unsigned long long* __restrict__ keys) {
  int n = blockIdx.x * 256 + threadIdx.x;
  int lane = threadIdx.x & 63;
  float pv[16], p2[16]; int pi[16];
  const float4* pv4 = (const float4*)(pval + (size_t)n * 16);
  const float4* p24 = (const float4*)(pm2  + (size_t)n * 16);
  const int4*   pi4 = (const int4*)  (pidx + (size_t)n * 16);
#pragma unroll
  for (int q = 0; q < 4; ++q) {
    float4 a = pv4[q]; float4 b = p24[q]; int4 c = pi4[q];
    pv[q*4+0]=a.x; pv[q*4+1]=a.y; pv[q*4+2]=a.z; pv[q*4+3]=a.w;
    p2[q*4+0]=b.x; p2[q*4+1]=b.y; p2[q*4+2]=b.z; p2[q*4+3]=b.w;
    pi[q*4+0]=c.x; pi[q*4+1]=c.y; pi[q*4+2]=c.z; pi[q*4+3]=c.w;
  }
  float a1 = FLT_MAX, a2 = FLT_MAX; int ai = 0x7fffffff;
#pragma unroll
  for (int c = 0; c < 16; ++c)
    top2_merge(a1, ai, a2, pv[c], pi[c], p2[c]);
  bool flg = (a2 - a1 <= MARGIN);
  float r = 0.f;
  if (flg) {
    keys[n] = ~0ull;
  } else {
    bins[n] = ai;
    atomicAdd(&counts[ai], 1);
    r = sqrtf(fmaxf(snorm[n] + a1, 0.f));
  }
  // flag_list append (wave-aggregated)
  {
    unsigned long long mask = __ballot(flg);
    if (mask) {
      int leader = __ffsll((unsigned long long)mask) - 1;
      int base = 0;
      if (lane == leader) base = atomicAdd(flag_count, __popcll(mask));
      base = __shfl(base, leader);
      if (flg) flag_list[base + __popcll(mask & ((1ull << lane) - 1))] = n;
    }
  }
  // worklist append: 128-cluster tiles that can contain the exact winner
#pragma unroll
  for (int c = 0; c < 16; ++c) {
    bool want = flg && (pv[c] <= a1 + MARGIN);
    unsigned long long mask = __ballot(want);
    if (mask) {
      int leader = __ffsll((unsigned long long)mask) - 1;
      int base = 0;
      if (lane == leader) base = atomicAdd(wl_count, __popcll(mask));
      base = __shfl(base, leader);
      if (want) worklist[base + __popcll(mask & ((1ull << lane) - 1))] = (n << 4) | c;
    }
  }
  for (int off = 32; off; off >>= 1) r += __shfl_down(r, off);
  if (lane == 0) atomicAdd(inertia, r);
}

// dense-worklist exact fp32 rescue: ONE ITEM PER WAVE; 2-level LDS reduce
// (no 64-lane shfl chains); key min-reduce hoisted out of the row loop.
__launch_bounds__(256)
__global__ void cleanup_work_kernel(const float* __restrict__ S, const float* __restrict__ M,
                                    const float* __restrict__ mnorm,
                                    const int* __restrict__ worklist, const int* __restrict__ wl_count,
                                    unsigned long long* __restrict__ keys) {
  __shared__ float red[4][64][9];        // [wave][src lane][rj], 9-stride: conflict-free
  const int t = threadIdx.x, lane = t & 63, wv = t >> 6;
  const int r8 = lane >> 3, c8 = lane & 7;
  const int items = *wl_count;
  for (int it = blockIdx.x * 4 + wv; it < items; it += gridDim.x * 4) {
    int wi = worklist[it];
    int n = wi >> 4, tile = wi & 15;
    const float4* sp = (const float4*)(S + (size_t)n * D_DIM + lane * 8);
    float4 s0 = sp[0], s1 = sp[1];
    int kb = tile * 128;
    unsigned long long bestkey = ~0ull;
    for (int ro = 0; ro < 16; ++ro) {
      float p[8];
#pragma unroll
      for (int rj = 0; rj < 8; ++rj) {
        const float4* mr = (const float4*)(M + (size_t)(kb + ro * 8 + rj) * D_DIM + lane * 8);
        float4 a = mr[0], b = mr[1];
        p[rj] = a.x*s0.x + a.y*s0.y + a.z*s0.z + a.w*s0.w
              + b.x*s1.x + b.y*s1.y + b.z*s1.z + b.w*s1.w;
      }
#pragma unroll
      for (int rj = 0; rj < 8; ++rj) red[wv][lane][rj] = p[rj];
      float ssum = 0.f;
#pragma unroll
      for (int i = 0; i < 8; ++i) ssum += red[wv][c8 * 8 + i][r8];
      ssum += __shfl_xor(ssum, 1);
      ssum += __shfl_xor(ssum, 2);
      ssum += __shfl_xor(ssum, 4);
      // all lanes now hold the full dot for row (kb + ro*8 + r8)
      int k = kb + ro * 8 + r8;
      float dist = mnorm[k] - 2.f * ssum;
      unsigned u = __float_as_uint(dist);
      u = (u >> 31) ? ~u : (u | 0x80000000u);
      unsigned long long key = ((unsigned long long)u << 32) | (unsigned)k;
      bestkey = bestkey < key ? bestkey : key;
    }
    // cross-row min (rows live in lane>>3 groups): masks 8,16,32
#pragma unroll
    for (int msk = 8; msk < 64; msk <<= 1) {
      unsigned long long o = (((unsigned long long)(unsigned)__shfl_xor((int)(bestkey >> 32), msk)) << 32)
                           | (unsigned)__shfl_xor((int)(bestkey & 0xffffffffu), msk);
      bestkey = bestkey < o ? bestkey : o;
    }
    if (lane == 0) atomicMin(keys + n, bestkey);
  }
}

// fused: resolve flagged winners (single block, grid-stride) + barrier +
// exclusive prefix scan over 2048 counts (first wave, shfl scan).
__launch_bounds__(256)
__global__ void resolve_prefix_kernel(const int* __restrict__ flag_list, const int* __restrict__ flag_count,
                                      const unsigned long long* __restrict__ keys,
                                      const float* __restrict__ snorm,
                                      int* __restrict__ bins, int* __restrict__ counts,
                                      float* __restrict__ inertia, int* __restrict__ cursor) {
  const int t = threadIdx.x;
  const int cnt = *flag_count;
  float r = 0.f;
  for (int i = t; i < cnt; i += 256) {
    int n = flag_list[i];
    unsigned long long key = keys[n];
    int k = (int)(unsigned)(key & 0xffffffffu);
    unsigned u = (unsigned)(key >> 32);
    u = (u >> 31) ? (u & 0x7fffffffu) : ~u;
    float dist = __uint_as_float(u);
    bins[n] = k;
    atomicAdd(&counts[k], 1);
    r += sqrtf(fmaxf(snorm[n] + dist, 0.f));
  }
  for (int off = 32; off; off >>= 1) r += __shfl_down(r, off);
  if ((t & 63) == 0) atomicAdd(inertia, r);
  __syncthreads();
  if (t < 64) {
    int loc[32]; int s = 0;
#pragma unroll
    for (int i = 0; i < 32; ++i) { loc[i] = s; s += counts[t * 32 + i]; }
    int tot = s;
#pragma unroll
    for (int off = 1; off < 64; off <<= 1) {
      int v = __shfl_up(tot, off);
      if (t >= off) tot += v;
    }
    int base = tot - s;
#pragma unroll
    for (int i = 0; i < 32; ++i) cursor[t * 32 + i] = base + loc[i];
  }
}

// bucket-fill: cluster-sorted sample list + per-slot cluster id
__global__ void fill_kernel(const int* __restrict__ bins, int* __restrict__ cursor,
                            int* __restrict__ bucket, int* __restrict__ bcl) {
  int n = blockIdx.x * 256 + threadIdx.x;
  int b = bins[n];
  int pos = atomicAdd(&cursor[b], 1);
  bucket[pos] = n;
  bcl[pos] = b;
}

// segment-scatter: each block owns a fixed 64-entry segment of the sorted bucket;
// register-accumulate runs of equal cluster, flush one atomicAdd per run.
__launch_bounds__(256)
__global__ void segscatter_kernel(const float* __restrict__ S, const int* __restrict__ bucket,
                                  const int* __restrict__ bcl, float* __restrict__ out) {
  __shared__ int sn[64], sk[64];
  const int t = threadIdx.x;
  const int i0 = blockIdx.x * 64;
  if (t < 64) { sn[t] = bucket[i0 + t]; sk[t] = bcl[i0 + t]; }
  __syncthreads();
  float a0 = 0.f, a1 = 0.f;
  int cur = sk[0];
  for (int i = 0; i < 64; ++i) {
    int k = sk[i];
    if (k != cur) {
      atomicAdd(&out[(size_t)cur * D_DIM + t], a0);
      atomicAdd(&out[(size_t)cur * D_DIM + t + 256], a1);
      a0 = 0.f; a1 = 0.f; cur = k;
    }
    const float* row = S + (size_t)sn[i] * D_DIM;
    a0 += row[t];
    a1 += row[t + 256];
  }
  atomicAdd(&out[(size_t)cur * D_DIM + t], a0);
  atomicAdd(&out[(size_t)cur * D_DIM + t + 256], a1);
}

// finalize: out currently holds cluster_sums; apply (sum + m*w)*alpha / keep-old rule
__global__ void finalize2_kernel(const float* __restrict__ M, const float* __restrict__ W,
                                 const int* __restrict__ counts, float* __restrict__ out) {
  int idx = blockIdx.x * 256 + threadIdx.x;
  int k = idx >> 9;
  int cnt = counts[k];
  float w = W[k];
  float nw = w + (float)cnt;
  float alpha = 1.f / ((nw == 0.f) ? 1.f : nw);
  float m = M[idx];
  float v = (out[idx] + m * w) * alpha;
  out[idx] = (cnt == 0) ? m : v;
}

// ============================================================ FALLBACK PATH (round-2)

#define TM    128
#define BK2   32
#define SPLIT 2
#define KPER  (K_C / SPLIT)
#define NKT   (KPER / TM)
#define NDT   (D_DIM / BK2)

__global__ void row_norms_kernel(const float* __restrict__ S, const float* __restrict__ M,
                                 float* __restrict__ snorm, float* __restrict__ mnorm) {
  int row  = blockIdx.x * 4 + (threadIdx.x >> 6);
  int lane = threadIdx.x & 63;
  if (row >= N_S + K_C) return;
  const float* src;
  float* dst;
  if (row < N_S) { src = S + (size_t)row * D_DIM; dst = snorm + row; }
  else { int r = row - N_S; src = M + (size_t)r * D_DIM; dst = mnorm + r; }
  float4 v0 = *(const float4*)(src + lane * 4);
  float4 v1 = *(const float4*)(src + 256 + lane * 4);
  float s = v0.x*v0.x + v0.y*v0.y + v0.z*v0.z + v0.w*v0.w
          + v1.x*v1.x + v1.y*v1.y + v1.z*v1.z + v1.w*v1.w;
  for (int off = 32; off; off >>= 1) s += __shfl_down(s, off);
  if (lane == 0) *dst = s;
}

__launch_bounds__(256)
__global__ void dist_argmin_kernel(const float* __restrict__ S, const float* __restrict__ M,
                                   const float* __restrict__ mnorm,
                                   float* __restrict__ pval, int* __restrict__ pidx,
                                   float* __restrict__ pm2) {
  __shared__ ushort tiles[2][4][TM * BK2];
  __shared__ float sm1[TM * 2];
  __shared__ float sm2[TM * 2];
  __shared__ int   si1[TM * 2];
  const int t    = threadIdx.x;
  const int lane = t & 63, wid = t >> 6;
  const int wr   = wid >> 1, wc = wid & 1;
  const int lx   = lane & 15, kg = lane >> 4;
  const int stile = blockIdx.x >> 1, split = blockIdx.x & 1;
  const int srow0 = stile * TM;
  const int kcol0 = split * KPER;
  for (int i = t; i < TM * 2; i += 256) { sm1[i] = FLT_MAX; sm2[i] = FLT_MAX; si1[i] = 0; }
  float4 av[4], bv[4];
#define LOADREGS(dtoff) do { \
    const float* Ag = S + (size_t)srow0 * D_DIM + (dtoff); \
    const float* Bg = M + (size_t)kbase * D_DIM + (dtoff); \
    _Pragma("unroll") \
    for (int q = 0; q < 4; ++q) { \
      int id = t + q * 256; int r_ = id >> 3, c_ = (id & 7) * 4; \
      av[q] = *(const float4*)(Ag + (size_t)r_ * D_DIM + c_); \
      bv[q] = *(const float4*)(Bg + (size_t)r_ * D_DIM + c_); \
    } } while (0)
#define WRITETILE(buf) do { \
    _Pragma("unroll") \
    for (int q = 0; q < 4; ++q) { \
      int id = t + q * 256; int r_ = id >> 3, c_ = (id & 7) * 4; \
      ushort4 h4, l4; \
      cvt_hl(av[q].x, h4.x, l4.x); cvt_hl(av[q].y, h4.y, l4.y); \
      cvt_hl(av[q].z, h4.z, l4.z); cvt_hl(av[q].w, h4.w, l4.w); \
      *(ushort4*)&tiles[buf][0][r_ * BK2 + c_] = h4; \
      *(ushort4*)&tiles[buf][1][r_ * BK2 + c_] = l4; \
      cvt_hl(bv[q].x, h4.x, l4.x); cvt_hl(bv[q].y, h4.y, l4.y); \
      cvt_hl(bv[q].z, h4.z, l4.z); cvt_hl(bv[q].w, h4.w, l4.w); \
      *(ushort4*)&tiles[buf][2][r_ * BK2 + c_] = h4; \
      *(ushort4*)&tiles[buf][3][r_ * BK2 + c_] = l4; \
    } } while (0)
  for (int kt = 0; kt < NKT; ++kt) {
    const int kbase = kcol0 + kt * TM;
    f32x4 acc[4][4];
#pragma unroll
    for (int i = 0; i < 4; ++i)
#pragma unroll
      for (int j = 0; j < 4; ++j) { acc[i][j][0] = 0.f; acc[i][j][1] = 0.f; acc[i][j][2] = 0.f; acc[i][j][3] = 0.f; }
    float mn[4];
#pragma unroll
    for (int ni = 0; ni < 4; ++ni) mn[ni] = mnorm[kbase + wc * 64 + ni * 16 + lx];
    LOADREGS(0);
    WRITETILE(0);
    __syncthreads();
    for (int di = 0; di < NDT; ++di) {
      const int cur = di & 1;
      if (di + 1 < NDT) LOADREGS((di + 1) * BK2);
      {
        s16x8 ah[4], al[4], bh[4], bl[4];
#pragma unroll
        for (int i = 0; i < 4; ++i) {
          ah[i] = *(const s16x8*)&tiles[cur][0][(wr * 64 + i * 16 + lx) * BK2 + kg * 8];
          al[i] = *(const s16x8*)&tiles[cur][1][(wr * 64 + i * 16 + lx) * BK2 + kg * 8];
          bh[i] = *(const s16x8*)&tiles[cur][2][(wc * 64 + i * 16 + lx) * BK2 + kg * 8];
          bl[i] = *(const s16x8*)&tiles[cur][3][(wc * 64 + i * 16 + lx) * BK2 + kg * 8];
        }
#pragma unroll
        for (int i = 0; i < 4; ++i)
#pragma unroll
          for (int j = 0; j < 4; ++j) {
            acc[i][j] = __builtin_amdgcn_mfma_f32_16x16x32_bf16(ah[i], bh[j], acc[i][j], 0, 0, 0);
            acc[i][j] = __builtin_amdgcn_mfma_f32_16x16x32_bf16(ah[i], bl[j], acc[i][j], 0, 0, 0);
            acc[i][j] = __builtin_amdgcn_mfma_f32_16x16x32_bf16(al[i], bh[j], acc[i][j], 0, 0, 0);
          }
      }
      if (di + 1 < NDT) { WRITETILE(cur ^ 1); __syncthreads(); }
    }
#pragma unroll
    for (int mi = 0; mi < 4; ++mi)
#pragma unroll
      for (int r = 0; r < 4; ++r) {
        float v1 = FLT_MAX, v2 = FLT_MAX; int i1 = 0;
#pragma unroll
        for (int ni = 0; ni < 4; ++ni) {
          float v = mn[ni] - 2.f * acc[mi][ni][r];
          int k = kbase + wc * 64 + ni * 16 + lx;
          if (v < v1) { v2 = v1; v1 = v; i1 = k; } else { v2 = fminf(v2, v); }
        }
#pragma unroll
        for (int msk = 1; msk < 16; msk <<= 1) {
          float o1 = __shfl_xor(v1, msk);
          int   oi = __shfl_xor(i1, msk);
          float o2 = __shfl_xor(v2, msk);
          top2_merge(v1, i1, v2, o1, oi, o2);
        }
        if (lx == 0) {
          int row = wr * 64 + mi * 16 + kg * 4 + r;
          int s = row * 2 + wc;
          float a1 = sm1[s], a2 = sm2[s]; int ai = si1[s];
          top2_merge(a1, ai, a2, v1, i1, v2);
          sm1[s] = a1; sm2[s] = a2; si1[s] = ai;
        }
      }
  }
  __syncthreads();
  if (t < TM) {
    float a1 = sm1[t * 2], a2 = sm2[t * 2]; int ai = si1[t * 2];
    top2_merge(a1, ai, a2, sm1[t * 2 + 1], si1[t * 2 + 1], sm2[t * 2 + 1]);
    int n = srow0 + t;
    pval[n * SPLIT + split] = a1;
    pidx[n * SPLIT + split] = ai;
    pm2[n * SPLIT + split]  = a2;
  }
#undef LOADREGS
#undef WRITETILE
}

__global__ void merge_bins_kernel(const float* __restrict__ pval, const int* __restrict__ pidx,
                                  const float* __restrict__ pm2, const float* __restrict__ snorm,
                                  int* __restrict__ bins, float* __restrict__ inertia,
                                  int* __restrict__ flag_list, int* __restrict__ flag_count) {
  int n = blockIdx.x * 256 + threadIdx.x;
  float a1 = pval[n * SPLIT], a2 = pm2[n * SPLIT]; int ai = pidx[n * SPLIT];
  top2_merge(a1, ai, a2, pval[n * SPLIT + 1], pidx[n * SPLIT + 1], pm2[n * SPLIT + 1]);
  float r = 0.f;
  if (a2 - a1 <= FB_MARGIN) {
    int idx = atomicAdd(flag_count, 1);
    flag_list[idx] = n;
  } else {
    bins[n] = ai;
    r = sqrtf(fmaxf(snorm[n] + a1, 0.f));
  }
  for (int off = 32; off; off >>= 1) r += __shfl_down(r, off);
  if ((threadIdx.x & 63) == 0) atomicAdd(inertia, r);
}

__launch_bounds__(256)
__global__ void cleanup_kernel(const float* __restrict__ S, const float* __restrict__ M,
                               const float* __restrict__ snorm, const float* __restrict__ mnorm,
                               const int* __restrict__ flag_list, const int* __restrict__ flag_count,
                               int* __restrict__ bins, float* __restrict__ inertia) {
  __shared__ float sS[D_DIM];
  __shared__ float wv[4];
  __shared__ int   wk[4];
  const int t = threadIdx.x, lane = t & 63, wid = t >> 6;
  const int cnt = *flag_count;
  for (int fi = blockIdx.x; fi < cnt; fi += gridDim.x) {
    int n = flag_list[fi];
    __syncthreads();
    for (int i = t; i < D_DIM; i += 256) sS[i] = S[(size_t)n * D_DIM + i];
    __syncthreads();
    float best = FLT_MAX; int bk = 0;
    for (int k = wid; k < K_C; k += 4) {
      const float* mr = M + (size_t)k * D_DIM;
      float4 m0 = *(const float4*)(mr + lane * 8);
      float4 m1 = *(const float4*)(mr + lane * 8 + 4);
      float4 s0 = *(const float4*)(sS + lane * 8);
      float4 s1 = *(const float4*)(sS + lane * 8 + 4);
      float p = m0.x*s0.x + m0.y*s0.y + m0.z*s0.z + m0.w*s0.w
              + m1.x*s1.x + m1.y*s1.y + m1.z*s1.z + m1.w*s1.w;
      for (int msk = 1; msk < 64; msk <<= 1) p += __shfl_xor(p, msk);
      float dist = mnorm[k] - 2.f * p;
      if (dist < best) { best = dist; bk = k; }
    }
    if (lane == 0) { wv[wid] = best; wk[wid] = bk; }
    __syncthreads();
    if (t == 0) {
      float b = wv[0]; int bi = wk[0];
      for (int w = 1; w < 4; ++w)
        if (wv[w] < b || (wv[w] == b && wk[w] < bi)) { b = wv[w]; bi = wk[w]; }
      bins[n] = bi;
      atomicAdd(inertia, sqrtf(fmaxf(snorm[n] + b, 0.f)));
    }
  }
}

__global__ void scatter_kernel(const float* __restrict__ S, const int* __restrict__ bins,
                               float* __restrict__ csum, float* __restrict__ counts) {
  int w    = (blockIdx.x * 256 + threadIdx.x) >> 6;
  int lane = threadIdx.x & 63;
  if (w >= N_S) return;
  int b = bins[w];
  const float* src = S + (size_t)w * D_DIM;
  float* dst = csum + (size_t)b * D_DIM;
#pragma unroll
  for (int c = 0; c < D_DIM; c += 64) atomicAdd(dst + c + lane, src[c + lane]);
  if (lane == 0) atomicAdd(counts + b, 1.0f);
}

__global__ void finalize_kernel(const float* __restrict__ M, const float* __restrict__ W,
                                const float* __restrict__ counts, float* __restrict__ out) {
  int idx = blockIdx.x * 256 + threadIdx.x;
  int k = idx >> 9;
  float cnt = counts[k];
  float w   = W[k];
  float nw  = w + cnt;
  float alpha = 1.f / ((nw == 0.f) ? 1.f : nw);
  float m = M[idx];
  float v = (out[idx] + m * w) * alpha;
  out[idx] = (cnt == 0.f) ? m : v;
}

// ================================================================= launcher

extern "C" void kernel_launch(void* const* d_in, const int* in_sizes, int n_in,
                              void* d_out, int out_size, void* d_ws, size_t ws_size,
                              hipStream_t stream) {
  const float* S = (const float*)d_in[0];
  const float* M = (const float*)d_in[1];
  const float* W = (const float*)d_in[2];
  float* out = (float*)d_out;
  char* ws = (char*)d_ws;

  const size_t oA  = 0;                                // A' hi 32 MiB
  const size_t oB  = oA  + (size_t)N_S * 1024;         // B' hi 2 MiB
  const size_t oPV = oB  + (size_t)K_C * 1024;         // pval [N][16]
  const size_t oPM = oPV + (size_t)N_S * 16 * 4;
  const size_t oPI = oPM + (size_t)N_S * 16 * 4;
  const size_t oSN = oPI + (size_t)N_S * 16 * 4;       // snorm
  const size_t oMN = oSN + (size_t)N_S * 4;            // mnorm
  const size_t oBI = oMN + (size_t)K_C * 4;            // bins
  const size_t oCU = oBI + (size_t)N_S * 4;            // cursor
  const size_t oBK = oCU + (size_t)K_C * 4;            // bucket
  const size_t oBC = oBK + (size_t)N_S * 4;            // bcl
  const size_t oFC = oBC + (size_t)N_S * 4;            // flag_count + wl_count (64B)
  const size_t oCN = oFC + 64;                         // counts 8KB (adjacent: one memset)
  const size_t oFL = oCN + (size_t)K_C * 4;            // flag_list
  const size_t oKY = oFL + (size_t)N_S * 4;            // keys (u64)
  const size_t oWL = oKY + (size_t)N_S * 8;            // worklist (up to 16 per sample)
  const size_t NEED = oWL + (size_t)N_S * 16 * 4;

  if (ws_size >= NEED) {
    ushort* Aq = (ushort*)(ws + oA);
    ushort* Bq = (ushort*)(ws + oB);
    float* pval = (float*)(ws + oPV);
    float* pm2  = (float*)(ws + oPM);
    int*   pidx = (int*)(ws + oPI);
    float* snorm = (float*)(ws + oSN);
    float* mnorm = (float*)(ws + oMN);
    int* bins   = (int*)(ws + oBI);
    int* cursor = (int*)(ws + oCU);
    int* bucket = (int*)(ws + oBK);
    int* bcl    = (int*)(ws + oBC);
    int* flag_count = (int*)(ws + oFC);
    int* wl_count   = flag_count + 1;
    int* counts = (int*)(ws + oCN);
    int* flag_list  = (int*)(ws + oFL);
    unsigned long long* keys = (unsigned long long*)(ws + oKY);
    int* worklist = (int*)(ws + oWL);

    hipMemsetAsync(d_out, 0, (size_t)(KD + 1) * sizeof(float), stream);
    hipMemsetAsync(flag_count, 0, 64 + (size_t)K_C * 4, stream);  // flags + counts

    preconvert_kernel<<<(N_S + K_C) / 4, 256, 0, stream>>>(S, M, Aq, Bq, snorm, mnorm);
    gemm_top2_kernel<<<4096, 256, 0, stream>>>(Aq, Bq, mnorm, pval, pidx, pm2);
    merge2_kernel<<<N_S / 256, 256, 0, stream>>>(pval, pidx, pm2, snorm, bins, out + KD,
                                                 counts, flag_list, flag_count,
                                                 worklist, wl_count, keys);
    cleanup_work_kernel<<<2048, 256, 0, stream>>>(S, M, mnorm, worklist, wl_count, keys);
    resolve_prefix_kernel<<<1, 256, 0, stream>>>(flag_list, flag_count, keys, snorm,
                                                 bins, counts, out + KD, cursor);
    fill_kernel<<<N_S / 256, 256, 0, stream>>>(bins, cursor, bucket, bcl);
    segscatter_kernel<<<N_S / 64, 256, 0, stream>>>(S, bucket, bcl, out);
    finalize2_kernel<<<KD / 256, 256, 0, stream>>>(M, W, counts, out);
  } else {
    float* mnorm     = (float*)ws;
    float* snorm     = mnorm + K_C;
    int*   bins      = (int*)(snorm + N_S);
    float* counts    = (float*)(bins + N_S);
    float* pval      = counts + K_C;
    int*   pidx      = (int*)(pval + (size_t)N_S * 2);
    float* pm2       = (float*)(pidx + (size_t)N_S * 2);
    int*   flag_count= (int*)(pm2 + (size_t)N_S * 2);
    int*   flag_list = flag_count + 16;

    hipMemsetAsync(d_out, 0, (size_t)(KD + 1) * sizeof(float), stream);
    hipMemsetAsync(counts, 0, K_C * sizeof(float), stream);
    hipMemsetAsync(flag_count, 0, sizeof(int), stream);

    row_norms_kernel<<<(N_S + K_C) / 4, 256, 0, stream>>>(S, M, snorm, mnorm);
    dist_argmin_kernel<<<(N_S / TM) * SPLIT, 256, 0, stream>>>(S, M, mnorm, pval, pidx, pm2);
    merge_bins_kernel<<<N_S / 256, 256, 0, stream>>>(pval, pidx, pm2, snorm, bins, out + KD,
                                                     flag_list, flag_count);
    cleanup_kernel<<<1024, 256, 0, stream>>>(S, M, snorm, mnorm, flag_list, flag_count,
                                             bins, out + KD);
    scatter_kernel<<<N_S / 4, 256, 0, stream>>>(S, bins, out, counts);
    finalize_kernel<<<KD / 256, 256, 0, stream>>>(M, W, counts, out);
  }
}